// Round 1
// baseline (2576.986 us; speedup 1.0000x reference)
//
#include <hip/hip_runtime.h>
#include <math.h>

#define BATCH 512
#define VEN 30000
#define VCN 20000
#define KT 100
#define HID 512
#define DIM 300

// ---------------- workspace layout (float offsets) ----------------
#define WS_H1_EN   0
#define WS_H2_EN   (WS_H1_EN + 262144)
#define WS_H1_CN   (WS_H2_EN + 262144)
#define WS_H2_CN   (WS_H1_CN + 262144)
#define WS_ROWS_EN (WS_H2_CN + 262144)      // 3*512 (sexp, sxr, sx)
#define WS_ROWS_CN (WS_ROWS_EN + 1536)
#define WS_SCAL    (WS_ROWS_CN + 1536)      // [0]=kl_en [1]=kl_cn [2]=closs [3]=ccount [4]=align [5]=recon_en [6]=recon_cn
#define ZERO_FLOATS (WS_SCAL + 64)          // everything below is atomically accumulated -> memset 0
#define WS_TEPADT  ZERO_FLOATS              // 300*128 (topic_emb transposed, k-padded to 128)
#define WS_WN2_EN  (WS_TEPADT + 38400)
#define WS_WN2_CN  (WS_WN2_EN + 30016)
#define WS_TN2     (WS_WN2_CN + 20032)      // 128
#define WS_TNBUF   (WS_TN2 + 128)           // 512*100 contrastive normalized thetas
#define WS_TNT     (WS_TNBUF + 51200)       // 100*300 normalized topic emb
#define WS_CTOP    (WS_TNT + 30000)         // 100*100 cost matrix
#define WS_COLSUM_EN (WS_CTOP + 10000)      // 128
#define WS_COLSUM_CN (WS_COLSUM_EN + 128)

// ---------------- output layout (float offsets) ----------------
#define OUT_THETA_EN 5
#define OUT_THETA_CN (OUT_THETA_EN + 51200)
#define OUT_BETA_EN  (OUT_THETA_CN + 51200)          // 102405, len 3,000,000
#define OUT_BETA_CN  (OUT_BETA_EN + 3000000)         // 3,102,405, len 2,000,000

__device__ __forceinline__ float waveReduceSum(float v) {
    #pragma unroll
    for (int o = 32; o > 0; o >>= 1) v += __shfl_down(v, o);
    return v;
}

// ================= generic fp32 tiled GEMM =================
// C[M,N] (+)= A[M,K] @ B[K,N] over k-chunk blockIdx.z.
// MODE 0: atomicAdd into C (split-K).  MODE 2: beta epilogue:
//   C is beta [KT][M]; writes exp(-sqrt(max(an2[m]+bn2[n]-2*acc,0))) at C[n*M+m], n<KT.
template <int MODE>
__global__ __launch_bounds__(256)
void gemm_tile(const float* __restrict__ A, const float* __restrict__ B,
               float* __restrict__ C, int M, int N, int Kdim, int kChunk,
               const float* __restrict__ an2, const float* __restrict__ bn2)
{
    __shared__ __align__(16) float As[16][68];   // [k][m]
    __shared__ __align__(16) float Bs[16][68];   // [k][n]
    const int tid = threadIdx.x;
    const int m0 = blockIdx.x * 64, n0 = blockIdx.y * 64;
    const int kStart = blockIdx.z * kChunk;
    const int kEnd = min(kStart + kChunk, Kdim);

    const int a_k = tid & 15;    // k within tile
    const int a_m = tid >> 4;    // m group
    const int b_n = tid & 63;
    const int b_k = tid >> 6;    // 0..3

    const int tm = (tid & 15) * 4;
    const int tn = (tid >> 4) * 4;

    float acc[4][4] = {};

    for (int k0 = kStart; k0 < kEnd; k0 += 16) {
        #pragma unroll
        for (int j = 0; j < 4; ++j) {
            int m = m0 + a_m + 16 * j;
            int kk = k0 + a_k;
            As[a_k][a_m + 16 * j] = (m < M && kk < kEnd) ? A[(size_t)m * Kdim + kk] : 0.f;
        }
        #pragma unroll
        for (int j = 0; j < 4; ++j) {
            int kk = k0 + b_k + 4 * j;
            int n = n0 + b_n;
            Bs[b_k + 4 * j][b_n] = (kk < kEnd && n < N) ? B[(size_t)kk * N + n] : 0.f;
        }
        __syncthreads();
        #pragma unroll
        for (int kk = 0; kk < 16; ++kk) {
            float4 a4 = *reinterpret_cast<const float4*>(&As[kk][tm]);
            float4 b4 = *reinterpret_cast<const float4*>(&Bs[kk][tn]);
            float av[4] = {a4.x, a4.y, a4.z, a4.w};
            float bv[4] = {b4.x, b4.y, b4.z, b4.w};
            #pragma unroll
            for (int i = 0; i < 4; ++i)
                #pragma unroll
                for (int j = 0; j < 4; ++j)
                    acc[i][j] += av[i] * bv[j];
        }
        __syncthreads();
    }

    if (MODE == 0) {
        #pragma unroll
        for (int i = 0; i < 4; ++i) {
            int m = m0 + tm + i;
            if (m < M) {
                #pragma unroll
                for (int j = 0; j < 4; ++j) {
                    int n = n0 + tn + j;
                    if (n < N) atomicAdd(&C[(size_t)m * N + n], acc[i][j]);
                }
            }
        }
    } else { // MODE 2: beta epilogue, transposed store
        #pragma unroll
        for (int i = 0; i < 4; ++i) {
            int m = m0 + tm + i;
            #pragma unroll
            for (int j = 0; j < 4; ++j) {
                int n = n0 + tn + j;
                if (m < M && n < KT) {
                    float sq = an2[m] + bn2[n] - 2.f * acc[i][j];
                    float d = sqrtf(fmaxf(sq, 0.f));
                    C[(size_t)n * M + m] = __expf(-d);   // tau = 1
                }
            }
        }
    }
}

// ================= small helpers =================
__global__ void build_tepadt_kernel(const float* __restrict__ te, float* __restrict__ tp)
{
    int idx = blockIdx.x * 256 + threadIdx.x;
    if (idx >= 300 * 128) return;
    int d = idx >> 7, k = idx & 127;
    tp[idx] = (k < KT) ? te[k * DIM + d] : 0.f;
}

__global__ void sqnorm_rows_kernel(const float* __restrict__ A, float* __restrict__ out,
                                   int rows, int cols)
{
    int r = blockIdx.x;
    if (r >= rows) { if (threadIdx.x == 0) out[r] = 0.f; return; }
    float s = 0.f;
    for (int d = threadIdx.x; d < cols; d += 64) { float a = A[(size_t)r * cols + d]; s += a * a; }
    s = waveReduceSum(s);
    if (threadIdx.x == 0) out[r] = s;
}

__global__ __launch_bounds__(256)
void colsum_kernel(const float* __restrict__ bta, float* __restrict__ cs, int V)
{
    int k = blockIdx.x, tid = threadIdx.x;
    float s = 0.f;
    for (int v = tid; v < V; v += 256) s += bta[(size_t)k * V + v];
    s = waveReduceSum(s);
    __shared__ float cw[4];
    if ((tid & 63) == 0) cw[tid >> 6] = s;
    __syncthreads();
    if (tid == 0) cs[k] = cw[0] + cw[1] + cw[2] + cw[3];
}

__global__ void normbeta_kernel(float* __restrict__ bta, const float* __restrict__ cs, int V)
{
    int v = blockIdx.x * 256 + threadIdx.x;
    int k = blockIdx.y;
    if (v < V) bta[(size_t)k * V + v] *= (1.0f / cs[k]);
}

__global__ void bias_softplus_kernel(float* __restrict__ y, const float* __restrict__ b, int n)
{
    int i = blockIdx.x * 256 + threadIdx.x;
    if (i < n) {
        float x = y[i] + b[i & (HID - 1)];
        y[i] = fmaxf(x, 0.f) + log1pf(__expf(-fabsf(x)));
    }
}

// ================= encoder head: mu/logvar/theta/KL =================
__global__ __launch_bounds__(128)
void encoder_head_kernel(const float* __restrict__ h2, const float* __restrict__ Wmu,
                         const float* __restrict__ bmu, const float* __restrict__ Wlv,
                         const float* __restrict__ blv, const float* __restrict__ eps,
                         float* __restrict__ theta_out, float* __restrict__ kl_accum)
{
    int i = blockIdx.x, tid = threadIdx.x;
    __shared__ float hrow[HID];
    __shared__ float sred[128];
    #pragma unroll
    for (int j = 0; j < 4; ++j) hrow[tid + 128 * j] = h2[i * HID + tid + 128 * j];
    __syncthreads();
    float mu = 0.f, lv = 0.f;
    if (tid < KT) {
        #pragma unroll 8
        for (int h = 0; h < HID; ++h) {
            float hv = hrow[h];
            mu += hv * Wmu[h * KT + tid];
            lv += hv * Wlv[h * KT + tid];
        }
        mu += bmu[tid]; lv += blv[tid];
    }
    float z = (tid < KT) ? (mu + eps[i * KT + tid] * __expf(0.5f * lv)) : -3.0e38f;
    sred[tid] = z; __syncthreads();
    for (int s = 64; s > 0; s >>= 1) { if (tid < s) sred[tid] = fmaxf(sred[tid], sred[tid + s]); __syncthreads(); }
    float zmax = sred[0]; __syncthreads();
    float e = (tid < KT) ? __expf(z - zmax) : 0.f;
    sred[tid] = e; __syncthreads();
    for (int s = 64; s > 0; s >>= 1) { if (tid < s) sred[tid] += sred[tid + s]; __syncthreads(); }
    float esum = sred[0]; __syncthreads();
    if (tid < KT) theta_out[i * KT + tid] = e / esum;
    float kterm = (tid < KT) ? 0.5f * (__expf(lv) + mu * mu - 1.f - lv) : 0.f;
    sred[tid] = kterm; __syncthreads();
    for (int s = 64; s > 0; s >>= 1) { if (tid < s) sred[tid] += sred[tid + s]; __syncthreads(); }
    if (tid == 0) atomicAdd(kl_accum, sred[0]);
}

// ================= recon loss (streamed theta@beta + online lse) =================
// thread owns vocab column v; bcol[100] in VGPRs; loops 128 rows in tiles of 8.
__global__ __launch_bounds__(256)
void recon_loss_kernel(const float* __restrict__ beta, const float* __restrict__ theta,
                       const float* __restrict__ x, int V, float* __restrict__ rows)
{
    int v = blockIdx.x * 256 + threadIdx.x;
    bool act = v < V;
    int vc = act ? v : 0;
    float bcol[KT];
    #pragma unroll
    for (int k = 0; k < KT; ++k) bcol[k] = beta[(size_t)k * V + vc];

    __shared__ __align__(16) float th[8][KT];
    int rowStart = blockIdx.y * 128;
    int lane = threadIdx.x & 63;

    for (int r0 = rowStart; r0 < rowStart + 128; r0 += 8) {
        __syncthreads();
        for (int t = threadIdx.x; t < 8 * KT; t += 256)
            th[t / KT][t % KT] = theta[(r0 + t / KT) * KT + (t % KT)];
        __syncthreads();
        #pragma unroll
        for (int i = 0; i < 8; ++i) {
            float r = 0.f;
            const float4* thv = reinterpret_cast<const float4*>(&th[i][0]);
            #pragma unroll
            for (int q = 0; q < 25; ++q) {
                float4 t4 = thv[q];
                r += bcol[4 * q] * t4.x + bcol[4 * q + 1] * t4.y
                   + bcol[4 * q + 2] * t4.z + bcol[4 * q + 3] * t4.w;
            }
            float xv = act ? x[(size_t)(r0 + i) * V + vc] : 0.f;
            float se = act ? __expf(r) : 0.f;
            float sxr = xv * r, sx = xv;
            se = waveReduceSum(se); sxr = waveReduceSum(sxr); sx = waveReduceSum(sx);
            if (lane == 0) {
                atomicAdd(&rows[r0 + i], se);
                atomicAdd(&rows[512 + r0 + i], sxr);
                atomicAdd(&rows[1024 + r0 + i], sx);
            }
        }
    }
}

__global__ __launch_bounds__(256)
void recon_finalize_kernel(const float* __restrict__ rows_en, const float* __restrict__ rows_cn,
                           float* __restrict__ scal)
{
    const float* rows = (blockIdx.x == 0) ? rows_en : rows_cn;
    int tid = threadIdx.x;
    float s = 0.f;
    for (int r = tid; r < 512; r += 256) {
        float se = rows[r], sxr = rows[512 + r], sx = rows[1024 + r];
        s += __logf(se) * sx - sxr;
    }
    s = waveReduceSum(s);
    __shared__ float cw[4];
    if ((tid & 63) == 0) cw[tid >> 6] = s;
    __syncthreads();
    if (tid == 0) scal[5 + blockIdx.x] = cw[0] + cw[1] + cw[2] + cw[3];
}

// ================= contrastive =================
__global__ __launch_bounds__(128)
void contrast_prep_kernel(const float* __restrict__ theta_en, const float* __restrict__ theta_cn,
                          float* __restrict__ tn)
{
    int i = blockIdx.x, tid = threadIdx.x;
    const float* src = ((i & 1) == 0) ? theta_en : theta_cn;
    float val = (tid < KT) ? src[i * KT + tid] : 0.f;
    __shared__ float sred[128];
    sred[tid] = val * val; __syncthreads();
    for (int s = 64; s > 0; s >>= 1) { if (tid < s) sred[tid] += sred[tid + s]; __syncthreads(); }
    float inv = 1.0f / fmaxf(sqrtf(sred[0]), 1e-8f);
    if (tid < KT) tn[i * KT + tid] = val * inv;
}

__global__ __launch_bounds__(256)
void contrast_main_kernel(const float* __restrict__ tn, const int* __restrict__ cid,
                          float* __restrict__ scal)
{
    int i = blockIdx.x, tid = threadIdx.x;
    __shared__ __align__(16) float ti[KT];
    if (tid < KT) ti[tid] = tn[i * KT + tid];
    __syncthreads();
    int ci = cid[i];
    bool vi = ci > 0;
    float pos = 0.f, neg = 0.f, pcnt = 0.f;
    for (int j = tid; j < 512; j += 256) {
        if (j == i) continue;
        float s = 0.f;
        const float4* tj = reinterpret_cast<const float4*>(&tn[j * KT]);
        #pragma unroll
        for (int q = 0; q < 25; ++q) {
            float4 t4 = tj[q];
            s += ti[4 * q] * t4.x + ti[4 * q + 1] * t4.y + ti[4 * q + 2] * t4.z + ti[4 * q + 3] * t4.w;
        }
        float E = __expf(s);   // tau = 1
        neg += E;
        if (vi && cid[j] == ci) { pos += E; pcnt += 1.f; }
    }
    pos = waveReduceSum(pos); neg = waveReduceSum(neg); pcnt = waveReduceSum(pcnt);
    __shared__ float cw[3][4];
    int w = tid >> 6;
    if ((tid & 63) == 0) { cw[0][w] = pos; cw[1][w] = neg; cw[2][w] = pcnt; }
    __syncthreads();
    if (tid == 0) {
        float P = 0.f, N = 0.f, PC = 0.f;
        for (int q = 0; q < 4; ++q) { P += cw[0][q]; N += cw[1][q]; PC += cw[2][q]; }
        if (vi && PC > 0.f) {
            atomicAdd(&scal[2], -__logf(P / (P + N + 1e-8f)));
            atomicAdd(&scal[3], 1.0f);
        }
    }
}

// ================= alignment / sinkhorn =================
__global__ void norm_rows_kernel(const float* __restrict__ A, float* __restrict__ out, int cols)
{
    int r = blockIdx.x, tid = threadIdx.x;   // 64 threads
    float s = 0.f;
    for (int d = tid; d < cols; d += 64) { float a = A[r * cols + d]; s += a * a; }
    s = waveReduceSum(s);
    s = __shfl(s, 0);
    float inv = 1.0f / fmaxf(sqrtf(s), 1e-8f);
    for (int d = tid; d < cols; d += 64) out[r * cols + d] = A[r * cols + d] * inv;
}

__global__ __launch_bounds__(128)
void ctopic_kernel(const float* __restrict__ tnt, float* __restrict__ C)
{
    int i = blockIdx.x, tid = threadIdx.x;
    __shared__ float ti[DIM];
    for (int d = tid; d < DIM; d += 128) ti[d] = tnt[i * DIM + d];
    __syncthreads();
    for (int j = tid; j < KT; j += 128) {
        float s = 0.f;
        for (int d = 0; d < DIM; ++d) s += ti[d] * tnt[j * DIM + d];
        C[i * KT + j] = 1.0f - s;
    }
}

__global__ __launch_bounds__(512)
void sinkhorn_kernel(const float* __restrict__ C, float* __restrict__ scal)
{
    __shared__ float Ks[KT * 101];
    __shared__ float Cs[KT * 101];
    __shared__ float u[KT], v[KT];
    int tid = threadIdx.x;
    for (int t = tid; t < KT * KT; t += 512) {
        int i = t / KT, j = t % KT;
        float c = C[t];
        Cs[i * 101 + j] = c;
        Ks[i * 101 + j] = __expf(-c * 10.0f);   // eps = 0.1
    }
    if (tid < KT) { u[tid] = 1.f; v[tid] = 1.f; }
    __syncthreads();
    int row = tid >> 2, q = tid & 3;
    bool act = tid < 400;
    for (int it = 0; it < 50; ++it) {
        if (act) {
            float s = 0.f;
            for (int j = q * 25; j < q * 25 + 25; ++j) s += Ks[row * 101 + j] * v[j];
            s += __shfl_xor(s, 1); s += __shfl_xor(s, 2);
            if (q == 0) u[row] = 0.01f / (s + 1e-8f);
        }
        __syncthreads();
        if (act) {
            float s = 0.f;
            for (int j = q * 25; j < q * 25 + 25; ++j) s += Ks[j * 101 + row] * u[j];
            s += __shfl_xor(s, 1); s += __shfl_xor(s, 2);
            if (q == 0) v[row] = 0.01f / (s + 1e-8f);
        }
        __syncthreads();
    }
    float part = 0.f;
    for (int t = tid; t < KT * KT; t += 512) {
        int i = t / KT, j = t % KT;
        part += u[i] * Ks[i * 101 + j] * v[j] * Cs[i * 101 + j];
    }
    part = waveReduceSum(part);
    __shared__ float cw[8];
    if ((tid & 63) == 0) cw[tid >> 6] = part;
    __syncthreads();
    if (tid == 0) {
        float s = 0.f;
        for (int w = 0; w < 8; ++w) s += cw[w];
        scal[4] = s;
    }
}

__global__ void final_combine_kernel(const float* __restrict__ scal, float* __restrict__ out)
{
    if (threadIdx.x == 0 && blockIdx.x == 0) {
        const float invB = 1.0f / 512.0f;
        float tm_en = scal[5] * invB + scal[0] * invB;
        float tm_cn = scal[6] * invB + scal[1] * invB;
        float contrast = scal[2] / (scal[3] + 1e-8f);
        float align = scal[4];
        out[0] = tm_en + tm_cn + contrast + align;
        out[1] = tm_en;
        out[2] = tm_cn;
        out[3] = contrast;
        out[4] = align;
    }
}

// ================= launch =================
extern "C" void kernel_launch(void* const* d_in, const int* in_sizes, int n_in,
                              void* d_out_v, int out_size, void* d_ws, size_t ws_size,
                              hipStream_t stream)
{
    const float* x_en   = (const float*)d_in[0];
    const float* x_cn   = (const float*)d_in[1];
    const int*   cid    = (const int*)  d_in[2];
    const float* eps_en = (const float*)d_in[3];
    const float* eps_cn = (const float*)d_in[4];
    const float* W1_en  = (const float*)d_in[5];
    const float* b1_en  = (const float*)d_in[6];
    const float* W2_en  = (const float*)d_in[7];
    const float* b2_en  = (const float*)d_in[8];
    const float* Wmu_en = (const float*)d_in[9];
    const float* bmu_en = (const float*)d_in[10];
    const float* Wlv_en = (const float*)d_in[11];
    const float* blv_en = (const float*)d_in[12];
    const float* W1_cn  = (const float*)d_in[13];
    const float* b1_cn  = (const float*)d_in[14];
    const float* W2_cn  = (const float*)d_in[15];
    const float* b2_cn  = (const float*)d_in[16];
    const float* Wmu_cn = (const float*)d_in[17];
    const float* bmu_cn = (const float*)d_in[18];
    const float* Wlv_cn = (const float*)d_in[19];
    const float* blv_cn = (const float*)d_in[20];
    const float* we_en  = (const float*)d_in[21];
    const float* we_cn  = (const float*)d_in[22];
    const float* te     = (const float*)d_in[23];
    float* out = (float*)d_out_v;
    float* ws  = (float*)d_ws;

    hipMemsetAsync(d_ws, 0, (size_t)ZERO_FLOATS * sizeof(float), stream);

    // ---- beta path ----
    build_tepadt_kernel<<<150, 256, 0, stream>>>(te, ws + WS_TEPADT);
    sqnorm_rows_kernel<<<VEN, 64, 0, stream>>>(we_en, ws + WS_WN2_EN, VEN, DIM);
    sqnorm_rows_kernel<<<VCN, 64, 0, stream>>>(we_cn, ws + WS_WN2_CN, VCN, DIM);
    sqnorm_rows_kernel<<<128, 64, 0, stream>>>(te, ws + WS_TN2, KT, DIM);
    gemm_tile<2><<<dim3(469, 2, 1), 256, 0, stream>>>(we_en, ws + WS_TEPADT, out + OUT_BETA_EN,
                                                      VEN, 128, DIM, DIM, ws + WS_WN2_EN, ws + WS_TN2);
    gemm_tile<2><<<dim3(313, 2, 1), 256, 0, stream>>>(we_cn, ws + WS_TEPADT, out + OUT_BETA_CN,
                                                      VCN, 128, DIM, DIM, ws + WS_WN2_CN, ws + WS_TN2);
    colsum_kernel<<<KT, 256, 0, stream>>>(out + OUT_BETA_EN, ws + WS_COLSUM_EN, VEN);
    colsum_kernel<<<KT, 256, 0, stream>>>(out + OUT_BETA_CN, ws + WS_COLSUM_CN, VCN);
    normbeta_kernel<<<dim3(118, KT), 256, 0, stream>>>(out + OUT_BETA_EN, ws + WS_COLSUM_EN, VEN);
    normbeta_kernel<<<dim3(79, KT), 256, 0, stream>>>(out + OUT_BETA_CN, ws + WS_COLSUM_CN, VCN);

    // ---- encoders ----
    gemm_tile<0><<<dim3(8, 8, 25), 256, 0, stream>>>(x_en, W1_en, ws + WS_H1_EN,
                                                     BATCH, HID, VEN, 1200, nullptr, nullptr);
    bias_softplus_kernel<<<1024, 256, 0, stream>>>(ws + WS_H1_EN, b1_en, 262144);
    gemm_tile<0><<<dim3(8, 8, 4), 256, 0, stream>>>(ws + WS_H1_EN, W2_en, ws + WS_H2_EN,
                                                    BATCH, HID, HID, 128, nullptr, nullptr);
    bias_softplus_kernel<<<1024, 256, 0, stream>>>(ws + WS_H2_EN, b2_en, 262144);
    encoder_head_kernel<<<BATCH, 128, 0, stream>>>(ws + WS_H2_EN, Wmu_en, bmu_en, Wlv_en, blv_en,
                                                   eps_en, out + OUT_THETA_EN, ws + WS_SCAL + 0);

    gemm_tile<0><<<dim3(8, 8, 25), 256, 0, stream>>>(x_cn, W1_cn, ws + WS_H1_CN,
                                                     BATCH, HID, VCN, 800, nullptr, nullptr);
    bias_softplus_kernel<<<1024, 256, 0, stream>>>(ws + WS_H1_CN, b1_cn, 262144);
    gemm_tile<0><<<dim3(8, 8, 4), 256, 0, stream>>>(ws + WS_H1_CN, W2_cn, ws + WS_H2_CN,
                                                    BATCH, HID, HID, 128, nullptr, nullptr);
    bias_softplus_kernel<<<1024, 256, 0, stream>>>(ws + WS_H2_CN, b2_cn, 262144);
    encoder_head_kernel<<<BATCH, 128, 0, stream>>>(ws + WS_H2_CN, Wmu_cn, bmu_cn, Wlv_cn, blv_cn,
                                                   eps_cn, out + OUT_THETA_CN, ws + WS_SCAL + 1);

    // ---- recon losses (need normalized beta + theta) ----
    recon_loss_kernel<<<dim3(118, 4), 256, 0, stream>>>(out + OUT_BETA_EN, out + OUT_THETA_EN,
                                                        x_en, VEN, ws + WS_ROWS_EN);
    recon_loss_kernel<<<dim3(79, 4), 256, 0, stream>>>(out + OUT_BETA_CN, out + OUT_THETA_CN,
                                                       x_cn, VCN, ws + WS_ROWS_CN);
    recon_finalize_kernel<<<2, 256, 0, stream>>>(ws + WS_ROWS_EN, ws + WS_ROWS_CN, ws + WS_SCAL);

    // ---- contrastive ----
    contrast_prep_kernel<<<BATCH, 128, 0, stream>>>(out + OUT_THETA_EN, out + OUT_THETA_CN, ws + WS_TNBUF);
    contrast_main_kernel<<<BATCH, 256, 0, stream>>>(ws + WS_TNBUF, cid, ws + WS_SCAL);

    // ---- alignment ----
    norm_rows_kernel<<<KT, 64, 0, stream>>>(te, ws + WS_TNT, DIM);
    ctopic_kernel<<<KT, 128, 0, stream>>>(ws + WS_TNT, ws + WS_CTOP);
    sinkhorn_kernel<<<1, 512, 0, stream>>>(ws + WS_CTOP, ws + WS_SCAL);

    final_combine_kernel<<<1, 64, 0, stream>>>(ws + WS_SCAL, out);
}

// Round 2
// 1803.579 us; speedup vs baseline: 1.4288x; 1.4288x over previous
//
#include <hip/hip_runtime.h>
#include <math.h>

#define BATCH 512
#define VEN 30000
#define VCN 20000
#define KT 100
#define HID 512
#define DIM 300
#define VENP 30080   // padded to 128
#define VCNP 20096
#define KDP 320      // DIM padded to mult of 32

typedef float f32x4 __attribute__((ext_vector_type(4)));
typedef short bf16x8 __attribute__((ext_vector_type(8)));
typedef unsigned short u16x8 __attribute__((ext_vector_type(8)));
typedef unsigned short u16x4 __attribute__((ext_vector_type(4)));

// ---------------- workspace layout (float offsets) ----------------
// zeroed prefix (atomicAdd targets)
#define WS_H1_EN   0
#define WS_H2_EN   (WS_H1_EN + 262144)
#define WS_H1_CN   (WS_H2_EN + 262144)
#define WS_H2_CN   (WS_H1_CN + 262144)
#define WS_ROWS_EN (WS_H2_CN + 262144)
#define WS_ROWS_CN (WS_ROWS_EN + 1536)
#define WS_SCAL    (WS_ROWS_CN + 1536)
#define ZERO_FLOATS (WS_SCAL + 64)
// BIG aliased region: phase 1 = XB (bf16 x), phase 2 = WEP/TEP (bf16 padded word emb)
#define WS_BIG     ZERO_FLOATS
#define XB_EN      WS_BIG                       // 15,360,000 u16 = 7,680,000 f
#define XB_CN      (WS_BIG + 7680000)           // 10,240,000 u16 = 5,120,000 f
#define WEP_EN     WS_BIG                       // 30080*320 u16 = 4,812,800 f
#define WEP_CN     (WS_BIG + 4812800)           // 20096*320 u16 = 3,215,360 f
#define TEP       (WS_BIG + 4812800 + 3215360)  // 128*320 u16 = 20,480 f
#define AFTER_BIG  (WS_BIG + 12800000)
#define W1T_EN     AFTER_BIG                    // 512*30000 u16 = 7,680,000 f
#define W1T_CN     (W1T_EN + 7680000)           // 512*20000 u16 = 5,120,000 f
#define W2T_EN     (W1T_CN + 5120000)           // 131072 f
#define W2T_CN     (W2T_EN + 131072)
#define H1B_EN     (W2T_CN + 131072)            // 512*512 u16 = 131072 f
#define H1B_CN     (H1B_EN + 131072)
#define WN2_EN     (H1B_CN + 131072)            // 30080
#define WN2_CN     (WN2_EN + 30080)             // 20096
#define TN2        (WN2_CN + 20096)             // 128
#define WS_TNBUF   (TN2 + 128)                  // 51200
#define WS_TNT     (WS_TNBUF + 51200)           // 30000
#define WS_CTOP    (WS_TNT + 30000)             // 10000
#define WS_COLSUM_EN (WS_CTOP + 10000)          // 128
#define WS_COLSUM_CN (WS_COLSUM_EN + 128)

// ---------------- output layout (float offsets) ----------------
#define OUT_THETA_EN 5
#define OUT_THETA_CN (OUT_THETA_EN + 51200)
#define OUT_BETA_EN  (OUT_THETA_CN + 51200)
#define OUT_BETA_CN  (OUT_BETA_EN + 3000000)

__device__ __forceinline__ float waveReduceSum(float v) {
    #pragma unroll
    for (int o = 32; o > 0; o >>= 1) v += __shfl_down(v, o);
    return v;
}

__device__ __forceinline__ unsigned short f2bf(float f) {
    unsigned int u = __float_as_uint(f);
    u = (u + 0x7FFFu + ((u >> 16) & 1u)) >> 16;   // RNE
    return (unsigned short)u;
}

// ================= bf16 MFMA GEMM (NT: A[M][ldA], B[N][ldB], both k-major) =======
// MODE 0: C[M][N] fp32 atomicAdd (split-K).
// MODE 2: beta epilogue: C[n*Mreal+m] = exp(-sqrt(max(an2[m]+bn2[n]-2acc,0))), n<KT, m<Mreal.
template <int MODE>
__global__ __launch_bounds__(256)
void mfma_gemm_nt(const unsigned short* __restrict__ A, const unsigned short* __restrict__ B,
                  float* __restrict__ C, int M, int N, int K, int ldA, int ldB, int chunkK,
                  int Mreal, const float* __restrict__ an2, const float* __restrict__ bn2)
{
    __shared__ __align__(16) unsigned short As[128 * 40];
    __shared__ __align__(16) unsigned short Bs[128 * 40];
    const int tid = threadIdx.x;
    const int m0 = blockIdx.x * 128, n0 = blockIdx.y * 128;
    const int kStart = blockIdx.z * chunkK;
    const int kEnd = min(kStart + chunkK, K);

    const int wave = tid >> 6, lane = tid & 63;
    const int wm = (wave & 1) * 64, wn = (wave >> 1) * 64;
    const int l15 = lane & 15, quad = lane >> 4;

    const int srow = tid >> 1;          // 0..127
    const int scol = (tid & 1) * 16;    // 0 or 16

    f32x4 acc[4][4];
    #pragma unroll
    for (int i = 0; i < 4; ++i)
        #pragma unroll
        for (int j = 0; j < 4; ++j)
            acc[i][j] = (f32x4){0.f, 0.f, 0.f, 0.f};

    const u16x8 z8 = {0,0,0,0,0,0,0,0};

    for (int k0 = kStart; k0 < kEnd; k0 += 32) {
        int kA = k0 + scol;
        // stage A (128 x 32)
        {
            const unsigned short* pa = A + (size_t)(m0 + srow) * ldA + kA;
            u16x8 a0 = (kA     < kEnd) ? *(const u16x8*)(pa)     : z8;
            u16x8 a1 = (kA + 8 < kEnd) ? *(const u16x8*)(pa + 8) : z8;
            *(u16x8*)&As[srow * 40 + scol]     = a0;
            *(u16x8*)&As[srow * 40 + scol + 8] = a1;
        }
        // stage B (128 x 32)
        {
            const unsigned short* pb = B + (size_t)(n0 + srow) * ldB + kA;
            u16x8 b0 = (kA     < kEnd) ? *(const u16x8*)(pb)     : z8;
            u16x8 b1 = (kA + 8 < kEnd) ? *(const u16x8*)(pb + 8) : z8;
            *(u16x8*)&Bs[srow * 40 + scol]     = b0;
            *(u16x8*)&Bs[srow * 40 + scol + 8] = b1;
        }
        __syncthreads();
        bf16x8 af[4], bfr[4];
        #pragma unroll
        for (int mi = 0; mi < 4; ++mi)
            af[mi] = *(const bf16x8*)&As[(wm + mi * 16 + l15) * 40 + quad * 8];
        #pragma unroll
        for (int ni = 0; ni < 4; ++ni)
            bfr[ni] = *(const bf16x8*)&Bs[(wn + ni * 16 + l15) * 40 + quad * 8];
        #pragma unroll
        for (int mi = 0; mi < 4; ++mi)
            #pragma unroll
            for (int ni = 0; ni < 4; ++ni)
                acc[mi][ni] = __builtin_amdgcn_mfma_f32_16x16x32_bf16(af[mi], bfr[ni], acc[mi][ni], 0, 0, 0);
        __syncthreads();
    }

    if (MODE == 0) {
        #pragma unroll
        for (int mi = 0; mi < 4; ++mi)
            #pragma unroll
            for (int ni = 0; ni < 4; ++ni)
                #pragma unroll
                for (int i = 0; i < 4; ++i) {
                    int m = m0 + wm + mi * 16 + quad * 4 + i;
                    int n = n0 + wn + ni * 16 + l15;
                    atomicAdd(&C[(size_t)m * N + n], acc[mi][ni][i]);
                }
    } else {
        #pragma unroll
        for (int mi = 0; mi < 4; ++mi)
            #pragma unroll
            for (int ni = 0; ni < 4; ++ni)
                #pragma unroll
                for (int i = 0; i < 4; ++i) {
                    int m = m0 + wm + mi * 16 + quad * 4 + i;
                    int n = n0 + wn + ni * 16 + l15;
                    if (m < Mreal && n < KT) {
                        float sq = an2[m] + bn2[n] - 2.f * acc[mi][ni][i];
                        C[(size_t)n * Mreal + m] = __expf(-sqrtf(fmaxf(sq, 0.f)));
                    }
                }
    }
}

// ================= cast / transpose kernels =================
__global__ __launch_bounds__(256)
void cast_bf16_kernel(const float* __restrict__ src, unsigned short* __restrict__ dst, int n4)
{
    int i = blockIdx.x * 256 + threadIdx.x;
    if (i < n4) {
        float4 v = reinterpret_cast<const float4*>(src)[i];
        u16x4 o = { f2bf(v.x), f2bf(v.y), f2bf(v.z), f2bf(v.w) };
        *(u16x4*)&dst[i * 4] = o;
    }
}

// src [K][N] f32 -> dst [N][K] bf16
__global__ __launch_bounds__(256)
void transpose_cast_kernel(const float* __restrict__ src, unsigned short* __restrict__ dst,
                           int K, int N)
{
    __shared__ float tile[32][33];
    int kb = blockIdx.x * 32, nb = blockIdx.y * 32;
    int tx = threadIdx.x & 31, ty4 = threadIdx.x >> 5;
    #pragma unroll
    for (int j = 0; j < 4; ++j) {
        int k = kb + ty4 * 4 + j;
        tile[ty4 * 4 + j][tx] = (k < K) ? src[(size_t)k * N + nb + tx] : 0.f;
    }
    __syncthreads();
    #pragma unroll
    for (int j = 0; j < 4; ++j) {
        int n = nb + ty4 * 4 + j;
        int k = kb + tx;
        if (k < K) dst[(size_t)n * K + k] = f2bf(tile[tx][ty4 * 4 + j]);
    }
}

// src [V][DIM] f32 -> dst [Mpad][KDP] bf16 zero-padded
__global__ void padcast_kernel(const float* __restrict__ src, unsigned short* __restrict__ dst, int V)
{
    int m = blockIdx.x, k = threadIdx.x;   // 320 threads
    float v = (m < V && k < DIM) ? src[(size_t)m * DIM + k] : 0.f;
    dst[(size_t)m * KDP + k] = f2bf(v);
}

__global__ void sqnorm_rows_kernel(const float* __restrict__ A, float* __restrict__ out,
                                   int rows, int cols)
{
    int r = blockIdx.x;
    float s = 0.f;
    for (int d = threadIdx.x; d < cols; d += 64) { float a = A[(size_t)r * cols + d]; s += a * a; }
    s = waveReduceSum(s);
    if (threadIdx.x == 0) out[r] = s;
}

__global__ __launch_bounds__(256)
void colsum_kernel(const float* __restrict__ bta, float* __restrict__ cs, int V)
{
    int k = blockIdx.x, tid = threadIdx.x;
    float s = 0.f;
    for (int v = tid; v < V; v += 256) s += bta[(size_t)k * V + v];
    s = waveReduceSum(s);
    __shared__ float cw[4];
    if ((tid & 63) == 0) cw[tid >> 6] = s;
    __syncthreads();
    if (tid == 0) cs[k] = cw[0] + cw[1] + cw[2] + cw[3];
}

__global__ void normbeta_kernel(float* __restrict__ bta, const float* __restrict__ cs, int V)
{
    int v = blockIdx.x * 256 + threadIdx.x;
    int k = blockIdx.y;
    if (v < V) bta[(size_t)k * V + v] *= (1.0f / cs[k]);
}

// bias + softplus; writes bf16
__global__ void bias_softplus_bf16_kernel(const float* __restrict__ src, const float* __restrict__ b,
                                          unsigned short* __restrict__ dst, int n)
{
    int i = blockIdx.x * 256 + threadIdx.x;
    if (i < n) {
        float x = src[i] + b[i & (HID - 1)];
        float sp = fmaxf(x, 0.f) + log1pf(__expf(-fabsf(x)));
        dst[i] = f2bf(sp);
    }
}

// bias + softplus in place fp32
__global__ void bias_softplus_f32_kernel(float* __restrict__ y, const float* __restrict__ b, int n)
{
    int i = blockIdx.x * 256 + threadIdx.x;
    if (i < n) {
        float x = y[i] + b[i & (HID - 1)];
        y[i] = fmaxf(x, 0.f) + log1pf(__expf(-fabsf(x)));
    }
}

// ================= encoder head =================
__global__ __launch_bounds__(128)
void encoder_head_kernel(const float* __restrict__ h2, const float* __restrict__ Wmu,
                         const float* __restrict__ bmu, const float* __restrict__ Wlv,
                         const float* __restrict__ blv, const float* __restrict__ eps,
                         float* __restrict__ theta_out, float* __restrict__ kl_accum)
{
    int i = blockIdx.x, tid = threadIdx.x;
    __shared__ float hrow[HID];
    __shared__ float sred[128];
    #pragma unroll
    for (int j = 0; j < 4; ++j) hrow[tid + 128 * j] = h2[i * HID + tid + 128 * j];
    __syncthreads();
    float mu = 0.f, lv = 0.f;
    if (tid < KT) {
        #pragma unroll 8
        for (int h = 0; h < HID; ++h) {
            float hv = hrow[h];
            mu += hv * Wmu[h * KT + tid];
            lv += hv * Wlv[h * KT + tid];
        }
        mu += bmu[tid]; lv += blv[tid];
    }
    float z = (tid < KT) ? (mu + eps[i * KT + tid] * __expf(0.5f * lv)) : -3.0e38f;
    sred[tid] = z; __syncthreads();
    for (int s = 64; s > 0; s >>= 1) { if (tid < s) sred[tid] = fmaxf(sred[tid], sred[tid + s]); __syncthreads(); }
    float zmax = sred[0]; __syncthreads();
    float e = (tid < KT) ? __expf(z - zmax) : 0.f;
    sred[tid] = e; __syncthreads();
    for (int s = 64; s > 0; s >>= 1) { if (tid < s) sred[tid] += sred[tid + s]; __syncthreads(); }
    float esum = sred[0]; __syncthreads();
    if (tid < KT) theta_out[i * KT + tid] = e / esum;
    float kterm = (tid < KT) ? 0.5f * (__expf(lv) + mu * mu - 1.f - lv) : 0.f;
    sred[tid] = kterm; __syncthreads();
    for (int s = 64; s > 0; s >>= 1) { if (tid < s) sred[tid] += sred[tid + s]; __syncthreads(); }
    if (tid == 0) atomicAdd(kl_accum, sred[0]);
}

// ================= recon loss =================
__global__ __launch_bounds__(256)
void recon_loss_kernel(const float* __restrict__ beta, const float* __restrict__ theta,
                       const float* __restrict__ x, int V, float* __restrict__ rows)
{
    int v = blockIdx.x * 256 + threadIdx.x;
    bool act = v < V;
    int vc = act ? v : 0;
    float bcol[KT];
    #pragma unroll
    for (int k = 0; k < KT; ++k) bcol[k] = beta[(size_t)k * V + vc];

    __shared__ __align__(16) float th[8][KT];
    int rowStart = blockIdx.y * 128;
    int lane = threadIdx.x & 63;

    for (int r0 = rowStart; r0 < rowStart + 128; r0 += 8) {
        __syncthreads();
        for (int t = threadIdx.x; t < 8 * KT; t += 256)
            th[t / KT][t % KT] = theta[(r0 + t / KT) * KT + (t % KT)];
        __syncthreads();
        #pragma unroll
        for (int i = 0; i < 8; ++i) {
            float r = 0.f;
            const float4* thv = reinterpret_cast<const float4*>(&th[i][0]);
            #pragma unroll
            for (int q = 0; q < 25; ++q) {
                float4 t4 = thv[q];
                r += bcol[4 * q] * t4.x + bcol[4 * q + 1] * t4.y
                   + bcol[4 * q + 2] * t4.z + bcol[4 * q + 3] * t4.w;
            }
            float xv = act ? x[(size_t)(r0 + i) * V + vc] : 0.f;
            float se = act ? __expf(r) : 0.f;
            float sxr = xv * r, sx = xv;
            se = waveReduceSum(se); sxr = waveReduceSum(sxr); sx = waveReduceSum(sx);
            if (lane == 0) {
                atomicAdd(&rows[r0 + i], se);
                atomicAdd(&rows[512 + r0 + i], sxr);
                atomicAdd(&rows[1024 + r0 + i], sx);
            }
        }
    }
}

__global__ __launch_bounds__(256)
void recon_finalize_kernel(const float* __restrict__ rows_en, const float* __restrict__ rows_cn,
                           float* __restrict__ scal)
{
    const float* rows = (blockIdx.x == 0) ? rows_en : rows_cn;
    int tid = threadIdx.x;
    float s = 0.f;
    for (int r = tid; r < 512; r += 256) {
        float se = rows[r], sxr = rows[512 + r], sx = rows[1024 + r];
        s += __logf(se) * sx - sxr;
    }
    s = waveReduceSum(s);
    __shared__ float cw[4];
    if ((tid & 63) == 0) cw[tid >> 6] = s;
    __syncthreads();
    if (tid == 0) scal[5 + blockIdx.x] = cw[0] + cw[1] + cw[2] + cw[3];
}

// ================= contrastive =================
__global__ __launch_bounds__(128)
void contrast_prep_kernel(const float* __restrict__ theta_en, const float* __restrict__ theta_cn,
                          float* __restrict__ tn)
{
    int i = blockIdx.x, tid = threadIdx.x;
    const float* src = ((i & 1) == 0) ? theta_en : theta_cn;
    float val = (tid < KT) ? src[i * KT + tid] : 0.f;
    __shared__ float sred[128];
    sred[tid] = val * val; __syncthreads();
    for (int s = 64; s > 0; s >>= 1) { if (tid < s) sred[tid] += sred[tid + s]; __syncthreads(); }
    float inv = 1.0f / fmaxf(sqrtf(sred[0]), 1e-8f);
    if (tid < KT) tn[i * KT + tid] = val * inv;
}

__global__ __launch_bounds__(256)
void contrast_main_kernel(const float* __restrict__ tn, const int* __restrict__ cid,
                          float* __restrict__ scal)
{
    int i = blockIdx.x, tid = threadIdx.x;
    __shared__ __align__(16) float ti[KT];
    if (tid < KT) ti[tid] = tn[i * KT + tid];
    __syncthreads();
    int ci = cid[i];
    bool vi = ci > 0;
    float pos = 0.f, neg = 0.f, pcnt = 0.f;
    for (int j = tid; j < 512; j += 256) {
        if (j == i) continue;
        float s = 0.f;
        const float4* tj = reinterpret_cast<const float4*>(&tn[j * KT]);
        #pragma unroll
        for (int q = 0; q < 25; ++q) {
            float4 t4 = tj[q];
            s += ti[4 * q] * t4.x + ti[4 * q + 1] * t4.y + ti[4 * q + 2] * t4.z + ti[4 * q + 3] * t4.w;
        }
        float E = __expf(s);
        neg += E;
        if (vi && cid[j] == ci) { pos += E; pcnt += 1.f; }
    }
    pos = waveReduceSum(pos); neg = waveReduceSum(neg); pcnt = waveReduceSum(pcnt);
    __shared__ float cw[3][4];
    int w = tid >> 6;
    if ((tid & 63) == 0) { cw[0][w] = pos; cw[1][w] = neg; cw[2][w] = pcnt; }
    __syncthreads();
    if (tid == 0) {
        float P = 0.f, N = 0.f, PC = 0.f;
        for (int q = 0; q < 4; ++q) { P += cw[0][q]; N += cw[1][q]; PC += cw[2][q]; }
        if (vi && PC > 0.f) {
            atomicAdd(&scal[2], -__logf(P / (P + N + 1e-8f)));
            atomicAdd(&scal[3], 1.0f);
        }
    }
}

// ================= alignment / sinkhorn =================
__global__ void norm_rows_kernel(const float* __restrict__ A, float* __restrict__ out, int cols)
{
    int r = blockIdx.x, tid = threadIdx.x;
    float s = 0.f;
    for (int d = tid; d < cols; d += 64) { float a = A[r * cols + d]; s += a * a; }
    s = waveReduceSum(s);
    s = __shfl(s, 0);
    float inv = 1.0f / fmaxf(sqrtf(s), 1e-8f);
    for (int d = tid; d < cols; d += 64) out[r * cols + d] = A[r * cols + d] * inv;
}

__global__ __launch_bounds__(128)
void ctopic_kernel(const float* __restrict__ tnt, float* __restrict__ C)
{
    int i = blockIdx.x, tid = threadIdx.x;
    __shared__ float ti[DIM];
    for (int d = tid; d < DIM; d += 128) ti[d] = tnt[i * DIM + d];
    __syncthreads();
    for (int j = tid; j < KT; j += 128) {
        float s = 0.f;
        for (int d = 0; d < DIM; ++d) s += ti[d] * tnt[j * DIM + d];
        C[i * KT + j] = 1.0f - s;
    }
}

__global__ __launch_bounds__(512)
void sinkhorn_kernel(const float* __restrict__ C, float* __restrict__ scal)
{
    __shared__ float Ks[KT * 101];
    __shared__ float Cs[KT * 101];
    __shared__ float u[KT], v[KT];
    int tid = threadIdx.x;
    for (int t = tid; t < KT * KT; t += 512) {
        int i = t / KT, j = t % KT;
        float c = C[t];
        Cs[i * 101 + j] = c;
        Ks[i * 101 + j] = __expf(-c * 10.0f);
    }
    if (tid < KT) { u[tid] = 1.f; v[tid] = 1.f; }
    __syncthreads();
    int row = tid >> 2, q = tid & 3;
    bool act = tid < 400;
    for (int it = 0; it < 50; ++it) {
        if (act) {
            float s = 0.f;
            for (int j = q * 25; j < q * 25 + 25; ++j) s += Ks[row * 101 + j] * v[j];
            s += __shfl_xor(s, 1); s += __shfl_xor(s, 2);
            if (q == 0) u[row] = 0.01f / (s + 1e-8f);
        }
        __syncthreads();
        if (act) {
            float s = 0.f;
            for (int j = q * 25; j < q * 25 + 25; ++j) s += Ks[j * 101 + row] * u[j];
            s += __shfl_xor(s, 1); s += __shfl_xor(s, 2);
            if (q == 0) v[row] = 0.01f / (s + 1e-8f);
        }
        __syncthreads();
    }
    float part = 0.f;
    for (int t = tid; t < KT * KT; t += 512) {
        int i = t / KT, j = t % KT;
        part += u[i] * Ks[i * 101 + j] * v[j] * Cs[i * 101 + j];
    }
    part = waveReduceSum(part);
    __shared__ float cw[8];
    if ((tid & 63) == 0) cw[tid >> 6] = part;
    __syncthreads();
    if (tid == 0) {
        float s = 0.f;
        for (int w = 0; w < 8; ++w) s += cw[w];
        scal[4] = s;
    }
}

__global__ void final_combine_kernel(const float* __restrict__ scal, float* __restrict__ out)
{
    if (threadIdx.x == 0 && blockIdx.x == 0) {
        const float invB = 1.0f / 512.0f;
        float tm_en = scal[5] * invB + scal[0] * invB;
        float tm_cn = scal[6] * invB + scal[1] * invB;
        float contrast = scal[2] / (scal[3] + 1e-8f);
        float align = scal[4];
        out[0] = tm_en + tm_cn + contrast + align;
        out[1] = tm_en;
        out[2] = tm_cn;
        out[3] = contrast;
        out[4] = align;
    }
}

// ================= launch =================
extern "C" void kernel_launch(void* const* d_in, const int* in_sizes, int n_in,
                              void* d_out_v, int out_size, void* d_ws, size_t ws_size,
                              hipStream_t stream)
{
    const float* x_en   = (const float*)d_in[0];
    const float* x_cn   = (const float*)d_in[1];
    const int*   cid    = (const int*)  d_in[2];
    const float* eps_en = (const float*)d_in[3];
    const float* eps_cn = (const float*)d_in[4];
    const float* W1_en  = (const float*)d_in[5];
    const float* b1_en  = (const float*)d_in[6];
    const float* W2_en  = (const float*)d_in[7];
    const float* b2_en  = (const float*)d_in[8];
    const float* Wmu_en = (const float*)d_in[9];
    const float* bmu_en = (const float*)d_in[10];
    const float* Wlv_en = (const float*)d_in[11];
    const float* blv_en = (const float*)d_in[12];
    const float* W1_cn  = (const float*)d_in[13];
    const float* b1_cn  = (const float*)d_in[14];
    const float* W2_cn  = (const float*)d_in[15];
    const float* b2_cn  = (const float*)d_in[16];
    const float* Wmu_cn = (const float*)d_in[17];
    const float* bmu_cn = (const float*)d_in[18];
    const float* Wlv_cn = (const float*)d_in[19];
    const float* blv_cn = (const float*)d_in[20];
    const float* we_en  = (const float*)d_in[21];
    const float* we_cn  = (const float*)d_in[22];
    const float* te     = (const float*)d_in[23];
    float* out = (float*)d_out_v;
    float* ws  = (float*)d_ws;

    unsigned short* xb_en  = (unsigned short*)(ws + XB_EN);
    unsigned short* xb_cn  = (unsigned short*)(ws + XB_CN);
    unsigned short* w1t_en = (unsigned short*)(ws + W1T_EN);
    unsigned short* w1t_cn = (unsigned short*)(ws + W1T_CN);
    unsigned short* w2t_en = (unsigned short*)(ws + W2T_EN);
    unsigned short* w2t_cn = (unsigned short*)(ws + W2T_CN);
    unsigned short* h1b_en = (unsigned short*)(ws + H1B_EN);
    unsigned short* h1b_cn = (unsigned short*)(ws + H1B_CN);
    unsigned short* wep_en = (unsigned short*)(ws + WEP_EN);
    unsigned short* wep_cn = (unsigned short*)(ws + WEP_CN);
    unsigned short* tep    = (unsigned short*)(ws + TEP);

    hipMemsetAsync(d_ws, 0, (size_t)ZERO_FLOATS * sizeof(float), stream);

    // ---- phase 1: encoder (uses XB alias of BIG region) ----
    cast_bf16_kernel<<<15000, 256, 0, stream>>>(x_en, xb_en, 3840000);
    cast_bf16_kernel<<<10000, 256, 0, stream>>>(x_cn, xb_cn, 2560000);
    transpose_cast_kernel<<<dim3(938, 16), 256, 0, stream>>>(W1_en, w1t_en, VEN, HID);
    transpose_cast_kernel<<<dim3(625, 16), 256, 0, stream>>>(W1_cn, w1t_cn, VCN, HID);
    transpose_cast_kernel<<<dim3(16, 16), 256, 0, stream>>>(W2_en, w2t_en, HID, HID);
    transpose_cast_kernel<<<dim3(16, 16), 256, 0, stream>>>(W2_cn, w2t_cn, HID, HID);

    mfma_gemm_nt<0><<<dim3(4, 4, 32), 256, 0, stream>>>(xb_en, w1t_en, ws + WS_H1_EN,
        BATCH, HID, VEN, VEN, VEN, 960, 0, nullptr, nullptr);
    mfma_gemm_nt<0><<<dim3(4, 4, 32), 256, 0, stream>>>(xb_cn, w1t_cn, ws + WS_H1_CN,
        BATCH, HID, VCN, VCN, VCN, 640, 0, nullptr, nullptr);

    bias_softplus_bf16_kernel<<<1024, 256, 0, stream>>>(ws + WS_H1_EN, b1_en, h1b_en, 262144);
    bias_softplus_bf16_kernel<<<1024, 256, 0, stream>>>(ws + WS_H1_CN, b1_cn, h1b_cn, 262144);

    mfma_gemm_nt<0><<<dim3(4, 4, 8), 256, 0, stream>>>(h1b_en, w2t_en, ws + WS_H2_EN,
        BATCH, HID, HID, HID, HID, 64, 0, nullptr, nullptr);
    mfma_gemm_nt<0><<<dim3(4, 4, 8), 256, 0, stream>>>(h1b_cn, w2t_cn, ws + WS_H2_CN,
        BATCH, HID, HID, HID, HID, 64, 0, nullptr, nullptr);

    bias_softplus_f32_kernel<<<1024, 256, 0, stream>>>(ws + WS_H2_EN, b2_en, 262144);
    bias_softplus_f32_kernel<<<1024, 256, 0, stream>>>(ws + WS_H2_CN, b2_cn, 262144);

    encoder_head_kernel<<<BATCH, 128, 0, stream>>>(ws + WS_H2_EN, Wmu_en, bmu_en, Wlv_en, blv_en,
                                                   eps_en, out + OUT_THETA_EN, ws + WS_SCAL + 0);
    encoder_head_kernel<<<BATCH, 128, 0, stream>>>(ws + WS_H2_CN, Wmu_cn, bmu_cn, Wlv_cn, blv_cn,
                                                   eps_cn, out + OUT_THETA_CN, ws + WS_SCAL + 1);

    // ---- phase 2: beta path (WEP/TEP overwrite XB region; gemm1s already done) ----
    padcast_kernel<<<VENP, KDP, 0, stream>>>(we_en, wep_en, VEN);
    padcast_kernel<<<VCNP, KDP, 0, stream>>>(we_cn, wep_cn, VCN);
    padcast_kernel<<<128, KDP, 0, stream>>>(te, tep, KT);
    sqnorm_rows_kernel<<<VEN, 64, 0, stream>>>(we_en, ws + WN2_EN, VEN, DIM);
    sqnorm_rows_kernel<<<VCN, 64, 0, stream>>>(we_cn, ws + WN2_CN, VCN, DIM);
    sqnorm_rows_kernel<<<KT, 64, 0, stream>>>(te, ws + TN2, KT, DIM);

    mfma_gemm_nt<2><<<dim3(235, 1, 1), 256, 0, stream>>>(wep_en, tep, out + OUT_BETA_EN,
        VENP, 128, KDP, KDP, KDP, KDP, VEN, ws + WN2_EN, ws + TN2);
    mfma_gemm_nt<2><<<dim3(157, 1, 1), 256, 0, stream>>>(wep_cn, tep, out + OUT_BETA_CN,
        VCNP, 128, KDP, KDP, KDP, KDP, VCN, ws + WN2_CN, ws + TN2);

    colsum_kernel<<<KT, 256, 0, stream>>>(out + OUT_BETA_EN, ws + WS_COLSUM_EN, VEN);
    colsum_kernel<<<KT, 256, 0, stream>>>(out + OUT_BETA_CN, ws + WS_COLSUM_CN, VCN);
    normbeta_kernel<<<dim3(118, KT), 256, 0, stream>>>(out + OUT_BETA_EN, ws + WS_COLSUM_EN, VEN);
    normbeta_kernel<<<dim3(79, KT), 256, 0, stream>>>(out + OUT_BETA_CN, ws + WS_COLSUM_CN, VCN);

    // ---- recon ----
    recon_loss_kernel<<<dim3(118, 4), 256, 0, stream>>>(out + OUT_BETA_EN, out + OUT_THETA_EN,
                                                        x_en, VEN, ws + WS_ROWS_EN);
    recon_loss_kernel<<<dim3(79, 4), 256, 0, stream>>>(out + OUT_BETA_CN, out + OUT_THETA_CN,
                                                       x_cn, VCN, ws + WS_ROWS_CN);
    recon_finalize_kernel<<<2, 256, 0, stream>>>(ws + WS_ROWS_EN, ws + WS_ROWS_CN, ws + WS_SCAL);

    // ---- contrastive ----
    contrast_prep_kernel<<<BATCH, 128, 0, stream>>>(out + OUT_THETA_EN, out + OUT_THETA_CN, ws + WS_TNBUF);
    contrast_main_kernel<<<BATCH, 256, 0, stream>>>(ws + WS_TNBUF, cid, ws + WS_SCAL);

    // ---- alignment ----
    norm_rows_kernel<<<KT, 64, 0, stream>>>(te, ws + WS_TNT, DIM);
    ctopic_kernel<<<KT, 128, 0, stream>>>(ws + WS_TNT, ws + WS_CTOP);
    sinkhorn_kernel<<<1, 512, 0, stream>>>(ws + WS_CTOP, ws + WS_SCAL);

    final_combine_kernel<<<1, 64, 0, stream>>>(ws + WS_SCAL, out);
}

// Round 3
// 927.702 us; speedup vs baseline: 2.7778x; 1.9441x over previous
//
#include <hip/hip_runtime.h>
#include <math.h>

#define BATCH 512
#define VEN 30000
#define VCN 20000
#define KT 100
#define HID 512
#define DIM 300
#define VENP 30080   // padded to 128
#define VCNP 20096
#define KDP 320      // DIM padded to mult of 32

typedef float f32x4 __attribute__((ext_vector_type(4)));
typedef short bf16x8 __attribute__((ext_vector_type(8)));
typedef unsigned short u16x8 __attribute__((ext_vector_type(8)));
typedef unsigned short u16x4 __attribute__((ext_vector_type(4)));

// ---------------- workspace layout (float offsets) ----------------
#define WS_H1_EN   0
#define WS_H2_EN   (WS_H1_EN + 262144)
#define WS_H1_CN   (WS_H2_EN + 262144)
#define WS_H2_CN   (WS_H1_CN + 262144)
#define WS_ROWS_EN (WS_H2_CN + 262144)
#define WS_ROWS_CN (WS_ROWS_EN + 1536)
#define WS_SCAL    (WS_ROWS_CN + 1536)
#define ZERO_FLOATS (WS_SCAL + 64)
// BIG aliased region: phase 1 = XB (bf16 x), phase 2 = WEP/TEP + BT/THP
#define WS_BIG     ZERO_FLOATS
#define XB_EN      WS_BIG                       // 7,680,000 f
#define XB_CN      (WS_BIG + 7680000)           // 5,120,000 f
#define WEP_EN     WS_BIG                       // 4,812,800 f
#define WEP_CN     (WS_BIG + 4812800)           // 3,215,360 f
#define TEP        (WS_BIG + 4812800 + 3215360) // 20,480 f
#define BT_EN      (WS_BIG + 8048640)           // 30080*128 u16 = 1,925,120 f
#define BT_CN      (BT_EN + 1925120)            // 20096*128 u16 = 1,286,144 f
#define THP_EN     (BT_CN + 1286144)            // 512*128 u16 = 32,768 f
#define THP_CN     (THP_EN + 32768)
#define AFTER_BIG  (WS_BIG + 12800000)
#define W1T_EN     AFTER_BIG                    // 7,680,000 f
#define W1T_CN     (W1T_EN + 7680000)           // 5,120,000 f
#define W2T_EN     (W1T_CN + 5120000)           // 131072 f
#define W2T_CN     (W2T_EN + 131072)
#define H1B_EN     (W2T_CN + 131072)
#define H1B_CN     (H1B_EN + 131072)
#define WN2_EN     (H1B_CN + 131072)            // 30080
#define WN2_CN     (WN2_EN + 30080)             // 20096
#define TN2        (WN2_CN + 20096)             // 128
#define WS_TNBUF   (TN2 + 128)                  // 51200
#define WS_TNT     (WS_TNBUF + 51200)           // 30000
#define WS_CTOP    (WS_TNT + 30000)             // 10000
#define WS_COLSUM_EN (WS_CTOP + 10000)          // 128
#define WS_COLSUM_CN (WS_COLSUM_EN + 128)

// ---------------- output layout (float offsets) ----------------
#define OUT_THETA_EN 5
#define OUT_THETA_CN (OUT_THETA_EN + 51200)
#define OUT_BETA_EN  (OUT_THETA_CN + 51200)
#define OUT_BETA_CN  (OUT_BETA_EN + 3000000)

__device__ __forceinline__ float waveReduceSum(float v) {
    #pragma unroll
    for (int o = 32; o > 0; o >>= 1) v += __shfl_down(v, o);
    return v;
}

__device__ __forceinline__ unsigned short f2bf(float f) {
    unsigned int u = __float_as_uint(f);
    u = (u + 0x7FFFu + ((u >> 16) & 1u)) >> 16;   // RNE
    return (unsigned short)u;
}

// ================= bf16 MFMA GEMM (NT) =================
template <int MODE>
__global__ __launch_bounds__(256)
void mfma_gemm_nt(const unsigned short* __restrict__ A, const unsigned short* __restrict__ B,
                  float* __restrict__ C, int M, int N, int K, int ldA, int ldB, int chunkK,
                  int Mreal, const float* __restrict__ an2, const float* __restrict__ bn2)
{
    __shared__ __align__(16) unsigned short As[128 * 40];
    __shared__ __align__(16) unsigned short Bs[128 * 40];
    const int tid = threadIdx.x;
    const int m0 = blockIdx.x * 128, n0 = blockIdx.y * 128;
    const int kStart = blockIdx.z * chunkK;
    const int kEnd = min(kStart + chunkK, K);

    const int wave = tid >> 6, lane = tid & 63;
    const int wm = (wave & 1) * 64, wn = (wave >> 1) * 64;
    const int l15 = lane & 15, quad = lane >> 4;

    const int srow = tid >> 1;
    const int scol = (tid & 1) * 16;

    f32x4 acc[4][4];
    #pragma unroll
    for (int i = 0; i < 4; ++i)
        #pragma unroll
        for (int j = 0; j < 4; ++j)
            acc[i][j] = (f32x4){0.f, 0.f, 0.f, 0.f};

    const u16x8 z8 = {0,0,0,0,0,0,0,0};

    for (int k0 = kStart; k0 < kEnd; k0 += 32) {
        int kA = k0 + scol;
        {
            const unsigned short* pa = A + (size_t)(m0 + srow) * ldA + kA;
            u16x8 a0 = (kA     < kEnd) ? *(const u16x8*)(pa)     : z8;
            u16x8 a1 = (kA + 8 < kEnd) ? *(const u16x8*)(pa + 8) : z8;
            *(u16x8*)&As[srow * 40 + scol]     = a0;
            *(u16x8*)&As[srow * 40 + scol + 8] = a1;
        }
        {
            const unsigned short* pb = B + (size_t)(n0 + srow) * ldB + kA;
            u16x8 b0 = (kA     < kEnd) ? *(const u16x8*)(pb)     : z8;
            u16x8 b1 = (kA + 8 < kEnd) ? *(const u16x8*)(pb + 8) : z8;
            *(u16x8*)&Bs[srow * 40 + scol]     = b0;
            *(u16x8*)&Bs[srow * 40 + scol + 8] = b1;
        }
        __syncthreads();
        bf16x8 af[4], bfr[4];
        #pragma unroll
        for (int mi = 0; mi < 4; ++mi)
            af[mi] = *(const bf16x8*)&As[(wm + mi * 16 + l15) * 40 + quad * 8];
        #pragma unroll
        for (int ni = 0; ni < 4; ++ni)
            bfr[ni] = *(const bf16x8*)&Bs[(wn + ni * 16 + l15) * 40 + quad * 8];
        #pragma unroll
        for (int mi = 0; mi < 4; ++mi)
            #pragma unroll
            for (int ni = 0; ni < 4; ++ni)
                acc[mi][ni] = __builtin_amdgcn_mfma_f32_16x16x32_bf16(af[mi], bfr[ni], acc[mi][ni], 0, 0, 0);
        __syncthreads();
    }

    if (MODE == 0) {
        #pragma unroll
        for (int mi = 0; mi < 4; ++mi)
            #pragma unroll
            for (int ni = 0; ni < 4; ++ni)
                #pragma unroll
                for (int i = 0; i < 4; ++i) {
                    int m = m0 + wm + mi * 16 + quad * 4 + i;
                    int n = n0 + wn + ni * 16 + l15;
                    atomicAdd(&C[(size_t)m * N + n], acc[mi][ni][i]);
                }
    } else {
        #pragma unroll
        for (int mi = 0; mi < 4; ++mi)
            #pragma unroll
            for (int ni = 0; ni < 4; ++ni)
                #pragma unroll
                for (int i = 0; i < 4; ++i) {
                    int m = m0 + wm + mi * 16 + quad * 4 + i;
                    int n = n0 + wn + ni * 16 + l15;
                    if (m < Mreal && n < KT) {
                        float sq = an2[m] + bn2[n] - 2.f * acc[mi][ni][i];
                        C[(size_t)n * Mreal + m] = __expf(-sqrtf(fmaxf(sq, 0.f)));
                    }
                }
    }
}

// ============ recon MFMA: r = betaT[V][K] x thetaPad[B][K]; fused loss sums ============
__global__ __launch_bounds__(256)
void recon_mfma_kernel(const unsigned short* __restrict__ A, const unsigned short* __restrict__ B,
                       const float* __restrict__ x, int V, float* __restrict__ rows)
{
    __shared__ __align__(16) unsigned short As[128 * 40];
    __shared__ __align__(16) unsigned short Bs[128 * 40];
    const int tid = threadIdx.x;
    const int m0 = blockIdx.x * 128, n0 = blockIdx.y * 128;
    const int wave = tid >> 6, lane = tid & 63;
    const int wm = (wave & 1) * 64, wn = (wave >> 1) * 64;
    const int l15 = lane & 15, quad = lane >> 4;
    const int srow = tid >> 1, scol = (tid & 1) * 16;

    f32x4 acc[4][4];
    #pragma unroll
    for (int i = 0; i < 4; ++i)
        #pragma unroll
        for (int j = 0; j < 4; ++j)
            acc[i][j] = (f32x4){0.f, 0.f, 0.f, 0.f};

    for (int k0 = 0; k0 < 128; k0 += 32) {
        int kA = k0 + scol;
        *(u16x8*)&As[srow * 40 + scol]     = *(const u16x8*)(A + (size_t)(m0 + srow) * 128 + kA);
        *(u16x8*)&As[srow * 40 + scol + 8] = *(const u16x8*)(A + (size_t)(m0 + srow) * 128 + kA + 8);
        *(u16x8*)&Bs[srow * 40 + scol]     = *(const u16x8*)(B + (size_t)(n0 + srow) * 128 + kA);
        *(u16x8*)&Bs[srow * 40 + scol + 8] = *(const u16x8*)(B + (size_t)(n0 + srow) * 128 + kA + 8);
        __syncthreads();
        bf16x8 af[4], bfr[4];
        #pragma unroll
        for (int mi = 0; mi < 4; ++mi)
            af[mi] = *(const bf16x8*)&As[(wm + mi * 16 + l15) * 40 + quad * 8];
        #pragma unroll
        for (int ni = 0; ni < 4; ++ni)
            bfr[ni] = *(const bf16x8*)&Bs[(wn + ni * 16 + l15) * 40 + quad * 8];
        #pragma unroll
        for (int mi = 0; mi < 4; ++mi)
            #pragma unroll
            for (int ni = 0; ni < 4; ++ni)
                acc[mi][ni] = __builtin_amdgcn_mfma_f32_16x16x32_bf16(af[mi], bfr[ni], acc[mi][ni], 0, 0, 0);
        __syncthreads();
    }

    #pragma unroll
    for (int ni = 0; ni < 4; ++ni) {
        int b = n0 + wn + ni * 16 + l15;
        float tse = 0.f, tsxr = 0.f, tsx = 0.f;
        #pragma unroll
        for (int mi = 0; mi < 4; ++mi) {
            int v0 = m0 + wm + mi * 16 + quad * 4;
            if (v0 + 3 < V) {
                float4 xv = *(const float4*)&x[(size_t)b * V + v0];
                float xa[4] = {xv.x, xv.y, xv.z, xv.w};
                #pragma unroll
                for (int i = 0; i < 4; ++i) {
                    float r = acc[mi][ni][i];
                    tse += __expf(r);
                    tsxr += xa[i] * r;
                    tsx  += xa[i];
                }
            } else {
                #pragma unroll
                for (int i = 0; i < 4; ++i) {
                    int v = v0 + i;
                    if (v < V) {
                        float xv1 = x[(size_t)b * V + v];
                        float r = acc[mi][ni][i];
                        tse += __expf(r); tsxr += xv1 * r; tsx += xv1;
                    }
                }
            }
        }
        tse  += __shfl_xor(tse, 16);  tse  += __shfl_xor(tse, 32);
        tsxr += __shfl_xor(tsxr, 16); tsxr += __shfl_xor(tsxr, 32);
        tsx  += __shfl_xor(tsx, 16);  tsx  += __shfl_xor(tsx, 32);
        if (quad == 0) {
            atomicAdd(&rows[b], tse);
            atomicAdd(&rows[512 + b], tsxr);
            atomicAdd(&rows[1024 + b], tsx);
        }
    }
}

// ================= cast / transpose kernels =================
__global__ __launch_bounds__(256)
void cast_bf16_kernel(const float* __restrict__ src, unsigned short* __restrict__ dst, int n4)
{
    int i = blockIdx.x * 256 + threadIdx.x;
    if (i < n4) {
        float4 v = reinterpret_cast<const float4*>(src)[i];
        u16x4 o = { f2bf(v.x), f2bf(v.y), f2bf(v.z), f2bf(v.w) };
        *(u16x4*)&dst[i * 4] = o;
    }
}

__global__ __launch_bounds__(256)
void transpose_cast_kernel(const float* __restrict__ src, unsigned short* __restrict__ dst,
                           int K, int N)
{
    __shared__ float tile[32][33];
    int kb = blockIdx.x * 32, nb = blockIdx.y * 32;
    int tx = threadIdx.x & 31, ty4 = threadIdx.x >> 5;
    #pragma unroll
    for (int j = 0; j < 4; ++j) {
        int k = kb + ty4 * 4 + j;
        tile[ty4 * 4 + j][tx] = (k < K) ? src[(size_t)k * N + nb + tx] : 0.f;
    }
    __syncthreads();
    #pragma unroll
    for (int j = 0; j < 4; ++j) {
        int n = nb + ty4 * 4 + j;
        int k = kb + tx;
        if (k < K) dst[(size_t)n * K + k] = f2bf(tile[tx][ty4 * 4 + j]);
    }
}

__global__ void padcast_kernel(const float* __restrict__ src, unsigned short* __restrict__ dst, int V)
{
    int m = blockIdx.x, k = threadIdx.x;   // 320 threads
    float v = (m < V && k < DIM) ? src[(size_t)m * DIM + k] : 0.f;
    dst[(size_t)m * KDP + k] = f2bf(v);
}

// beta [KT][V] f32 (normalized) -> bt [Vp][128] bf16 zero-padded
__global__ __launch_bounds__(256)
void beta_to_bt_kernel(const float* __restrict__ beta, unsigned short* __restrict__ bt,
                       int V)
{
    int v = blockIdx.x * 64 + (threadIdx.x & 63);
    int kq = threadIdx.x >> 6;   // 0..3 -> k chunk of 32
    unsigned short tmp[32];
    #pragma unroll
    for (int j = 0; j < 32; ++j) {
        int k = kq * 32 + j;
        float val = (k < KT && v < V) ? beta[(size_t)k * V + v] : 0.f;
        tmp[j] = f2bf(val);
    }
    #pragma unroll
    for (int q = 0; q < 4; ++q)
        *(u16x8*)&bt[(size_t)v * 128 + kq * 32 + q * 8] = *(u16x8*)&tmp[q * 8];
}

__global__ void theta_pad_kernel(const float* __restrict__ theta, unsigned short* __restrict__ thp)
{
    int idx = blockIdx.x * 256 + threadIdx.x;  // 65536 total
    int b = idx >> 7, k = idx & 127;
    thp[idx] = f2bf(k < KT ? theta[b * KT + k] : 0.f);
}

__global__ void sqnorm_rows_kernel(const float* __restrict__ A, float* __restrict__ out,
                                   int rows, int cols)
{
    int r = blockIdx.x;
    float s = 0.f;
    for (int d = threadIdx.x; d < cols; d += 64) { float a = A[(size_t)r * cols + d]; s += a * a; }
    s = waveReduceSum(s);
    if (threadIdx.x == 0) out[r] = s;
}

__global__ __launch_bounds__(256)
void colsum_kernel(const float* __restrict__ bta, float* __restrict__ cs, int V)
{
    int k = blockIdx.x, tid = threadIdx.x;
    float s = 0.f;
    for (int v = tid; v < V; v += 256) s += bta[(size_t)k * V + v];
    s = waveReduceSum(s);
    __shared__ float cw[4];
    if ((tid & 63) == 0) cw[tid >> 6] = s;
    __syncthreads();
    if (tid == 0) cs[k] = cw[0] + cw[1] + cw[2] + cw[3];
}

__global__ void normbeta_kernel(float* __restrict__ bta, const float* __restrict__ cs, int V)
{
    int v = blockIdx.x * 256 + threadIdx.x;
    int k = blockIdx.y;
    if (v < V) bta[(size_t)k * V + v] *= (1.0f / cs[k]);
}

__global__ void bias_softplus_bf16_kernel(const float* __restrict__ src, const float* __restrict__ b,
                                          unsigned short* __restrict__ dst, int n)
{
    int i = blockIdx.x * 256 + threadIdx.x;
    if (i < n) {
        float x = src[i] + b[i & (HID - 1)];
        float sp = fmaxf(x, 0.f) + log1pf(__expf(-fabsf(x)));
        dst[i] = f2bf(sp);
    }
}

__global__ void bias_softplus_f32_kernel(float* __restrict__ y, const float* __restrict__ b, int n)
{
    int i = blockIdx.x * 256 + threadIdx.x;
    if (i < n) {
        float x = y[i] + b[i & (HID - 1)];
        y[i] = fmaxf(x, 0.f) + log1pf(__expf(-fabsf(x)));
    }
}

// ================= encoder head =================
__global__ __launch_bounds__(128)
void encoder_head_kernel(const float* __restrict__ h2, const float* __restrict__ Wmu,
                         const float* __restrict__ bmu, const float* __restrict__ Wlv,
                         const float* __restrict__ blv, const float* __restrict__ eps,
                         float* __restrict__ theta_out, float* __restrict__ kl_accum)
{
    int i = blockIdx.x, tid = threadIdx.x;
    __shared__ float hrow[HID];
    __shared__ float sred[128];
    #pragma unroll
    for (int j = 0; j < 4; ++j) hrow[tid + 128 * j] = h2[i * HID + tid + 128 * j];
    __syncthreads();
    float mu = 0.f, lv = 0.f;
    if (tid < KT) {
        #pragma unroll 8
        for (int h = 0; h < HID; ++h) {
            float hv = hrow[h];
            mu += hv * Wmu[h * KT + tid];
            lv += hv * Wlv[h * KT + tid];
        }
        mu += bmu[tid]; lv += blv[tid];
    }
    float z = (tid < KT) ? (mu + eps[i * KT + tid] * __expf(0.5f * lv)) : -3.0e38f;
    sred[tid] = z; __syncthreads();
    for (int s = 64; s > 0; s >>= 1) { if (tid < s) sred[tid] = fmaxf(sred[tid], sred[tid + s]); __syncthreads(); }
    float zmax = sred[0]; __syncthreads();
    float e = (tid < KT) ? __expf(z - zmax) : 0.f;
    sred[tid] = e; __syncthreads();
    for (int s = 64; s > 0; s >>= 1) { if (tid < s) sred[tid] += sred[tid + s]; __syncthreads(); }
    float esum = sred[0]; __syncthreads();
    if (tid < KT) theta_out[i * KT + tid] = e / esum;
    float kterm = (tid < KT) ? 0.5f * (__expf(lv) + mu * mu - 1.f - lv) : 0.f;
    sred[tid] = kterm; __syncthreads();
    for (int s = 64; s > 0; s >>= 1) { if (tid < s) sred[tid] += sred[tid + s]; __syncthreads(); }
    if (tid == 0) atomicAdd(kl_accum, sred[0]);
}

__global__ __launch_bounds__(256)
void recon_finalize_kernel(const float* __restrict__ rows_en, const float* __restrict__ rows_cn,
                           float* __restrict__ scal)
{
    const float* rows = (blockIdx.x == 0) ? rows_en : rows_cn;
    int tid = threadIdx.x;
    float s = 0.f;
    for (int r = tid; r < 512; r += 256) {
        float se = rows[r], sxr = rows[512 + r], sx = rows[1024 + r];
        s += __logf(se) * sx - sxr;
    }
    s = waveReduceSum(s);
    __shared__ float cw[4];
    if ((tid & 63) == 0) cw[tid >> 6] = s;
    __syncthreads();
    if (tid == 0) scal[5 + blockIdx.x] = cw[0] + cw[1] + cw[2] + cw[3];
}

// ================= contrastive =================
__global__ __launch_bounds__(128)
void contrast_prep_kernel(const float* __restrict__ theta_en, const float* __restrict__ theta_cn,
                          float* __restrict__ tn)
{
    int i = blockIdx.x, tid = threadIdx.x;
    const float* src = ((i & 1) == 0) ? theta_en : theta_cn;
    float val = (tid < KT) ? src[i * KT + tid] : 0.f;
    __shared__ float sred[128];
    sred[tid] = val * val; __syncthreads();
    for (int s = 64; s > 0; s >>= 1) { if (tid < s) sred[tid] += sred[tid + s]; __syncthreads(); }
    float inv = 1.0f / fmaxf(sqrtf(sred[0]), 1e-8f);
    if (tid < KT) tn[i * KT + tid] = val * inv;
}

__global__ __launch_bounds__(256)
void contrast_main_kernel(const float* __restrict__ tn, const int* __restrict__ cid,
                          float* __restrict__ scal)
{
    int i = blockIdx.x, tid = threadIdx.x;
    __shared__ __align__(16) float ti[KT];
    if (tid < KT) ti[tid] = tn[i * KT + tid];
    __syncthreads();
    int ci = cid[i];
    bool vi = ci > 0;
    float pos = 0.f, neg = 0.f, pcnt = 0.f;
    for (int j = tid; j < 512; j += 256) {
        if (j == i) continue;
        float s = 0.f;
        const float4* tj = reinterpret_cast<const float4*>(&tn[j * KT]);
        #pragma unroll
        for (int q = 0; q < 25; ++q) {
            float4 t4 = tj[q];
            s += ti[4 * q] * t4.x + ti[4 * q + 1] * t4.y + ti[4 * q + 2] * t4.z + ti[4 * q + 3] * t4.w;
        }
        float E = __expf(s);
        neg += E;
        if (vi && cid[j] == ci) { pos += E; pcnt += 1.f; }
    }
    pos = waveReduceSum(pos); neg = waveReduceSum(neg); pcnt = waveReduceSum(pcnt);
    __shared__ float cw[3][4];
    int w = tid >> 6;
    if ((tid & 63) == 0) { cw[0][w] = pos; cw[1][w] = neg; cw[2][w] = pcnt; }
    __syncthreads();
    if (tid == 0) {
        float P = 0.f, N = 0.f, PC = 0.f;
        for (int q = 0; q < 4; ++q) { P += cw[0][q]; N += cw[1][q]; PC += cw[2][q]; }
        if (vi && PC > 0.f) {
            atomicAdd(&scal[2], -__logf(P / (P + N + 1e-8f)));
            atomicAdd(&scal[3], 1.0f);
        }
    }
}

// ================= alignment / sinkhorn =================
__global__ void norm_rows_kernel(const float* __restrict__ A, float* __restrict__ out, int cols)
{
    int r = blockIdx.x, tid = threadIdx.x;
    float s = 0.f;
    for (int d = tid; d < cols; d += 64) { float a = A[r * cols + d]; s += a * a; }
    s = waveReduceSum(s);
    s = __shfl(s, 0);
    float inv = 1.0f / fmaxf(sqrtf(s), 1e-8f);
    for (int d = tid; d < cols; d += 64) out[r * cols + d] = A[r * cols + d] * inv;
}

__global__ __launch_bounds__(128)
void ctopic_kernel(const float* __restrict__ tnt, float* __restrict__ C)
{
    int i = blockIdx.x, tid = threadIdx.x;
    __shared__ float ti[DIM];
    for (int d = tid; d < DIM; d += 128) ti[d] = tnt[i * DIM + d];
    __syncthreads();
    for (int j = tid; j < KT; j += 128) {
        float s = 0.f;
        for (int d = 0; d < DIM; ++d) s += ti[d] * tnt[j * DIM + d];
        C[i * KT + j] = 1.0f - s;
    }
}

__global__ __launch_bounds__(512)
void sinkhorn_kernel(const float* __restrict__ C, float* __restrict__ scal)
{
    __shared__ float Ks[KT * 101];
    __shared__ float Cs[KT * 101];
    __shared__ float u[KT], v[KT];
    int tid = threadIdx.x;
    for (int t = tid; t < KT * KT; t += 512) {
        int i = t / KT, j = t % KT;
        float c = C[t];
        Cs[i * 101 + j] = c;
        Ks[i * 101 + j] = __expf(-c * 10.0f);
    }
    if (tid < KT) { u[tid] = 1.f; v[tid] = 1.f; }
    __syncthreads();
    int row = tid >> 2, q = tid & 3;
    bool act = tid < 400;
    for (int it = 0; it < 50; ++it) {
        if (act) {
            float s = 0.f;
            for (int j = q * 25; j < q * 25 + 25; ++j) s += Ks[row * 101 + j] * v[j];
            s += __shfl_xor(s, 1); s += __shfl_xor(s, 2);
            if (q == 0) u[row] = 0.01f / (s + 1e-8f);
        }
        __syncthreads();
        if (act) {
            float s = 0.f;
            for (int j = q * 25; j < q * 25 + 25; ++j) s += Ks[j * 101 + row] * u[j];
            s += __shfl_xor(s, 1); s += __shfl_xor(s, 2);
            if (q == 0) v[row] = 0.01f / (s + 1e-8f);
        }
        __syncthreads();
    }
    float part = 0.f;
    for (int t = tid; t < KT * KT; t += 512) {
        int i = t / KT, j = t % KT;
        part += u[i] * Ks[i * 101 + j] * v[j] * Cs[i * 101 + j];
    }
    part = waveReduceSum(part);
    __shared__ float cw[8];
    if ((tid & 63) == 0) cw[tid >> 6] = part;
    __syncthreads();
    if (tid == 0) {
        float s = 0.f;
        for (int w = 0; w < 8; ++w) s += cw[w];
        scal[4] = s;
    }
}

__global__ void final_combine_kernel(const float* __restrict__ scal, float* __restrict__ out)
{
    if (threadIdx.x == 0 && blockIdx.x == 0) {
        const float invB = 1.0f / 512.0f;
        float tm_en = scal[5] * invB + scal[0] * invB;
        float tm_cn = scal[6] * invB + scal[1] * invB;
        float contrast = scal[2] / (scal[3] + 1e-8f);
        float align = scal[4];
        out[0] = tm_en + tm_cn + contrast + align;
        out[1] = tm_en;
        out[2] = tm_cn;
        out[3] = contrast;
        out[4] = align;
    }
}

// ================= launch =================
extern "C" void kernel_launch(void* const* d_in, const int* in_sizes, int n_in,
                              void* d_out_v, int out_size, void* d_ws, size_t ws_size,
                              hipStream_t stream)
{
    const float* x_en   = (const float*)d_in[0];
    const float* x_cn   = (const float*)d_in[1];
    const int*   cid    = (const int*)  d_in[2];
    const float* eps_en = (const float*)d_in[3];
    const float* eps_cn = (const float*)d_in[4];
    const float* W1_en  = (const float*)d_in[5];
    const float* b1_en  = (const float*)d_in[6];
    const float* W2_en  = (const float*)d_in[7];
    const float* b2_en  = (const float*)d_in[8];
    const float* Wmu_en = (const float*)d_in[9];
    const float* bmu_en = (const float*)d_in[10];
    const float* Wlv_en = (const float*)d_in[11];
    const float* blv_en = (const float*)d_in[12];
    const float* W1_cn  = (const float*)d_in[13];
    const float* b1_cn  = (const float*)d_in[14];
    const float* W2_cn  = (const float*)d_in[15];
    const float* b2_cn  = (const float*)d_in[16];
    const float* Wmu_cn = (const float*)d_in[17];
    const float* bmu_cn = (const float*)d_in[18];
    const float* Wlv_cn = (const float*)d_in[19];
    const float* blv_cn = (const float*)d_in[20];
    const float* we_en  = (const float*)d_in[21];
    const float* we_cn  = (const float*)d_in[22];
    const float* te     = (const float*)d_in[23];
    float* out = (float*)d_out_v;
    float* ws  = (float*)d_ws;

    unsigned short* xb_en  = (unsigned short*)(ws + XB_EN);
    unsigned short* xb_cn  = (unsigned short*)(ws + XB_CN);
    unsigned short* w1t_en = (unsigned short*)(ws + W1T_EN);
    unsigned short* w1t_cn = (unsigned short*)(ws + W1T_CN);
    unsigned short* w2t_en = (unsigned short*)(ws + W2T_EN);
    unsigned short* w2t_cn = (unsigned short*)(ws + W2T_CN);
    unsigned short* h1b_en = (unsigned short*)(ws + H1B_EN);
    unsigned short* h1b_cn = (unsigned short*)(ws + H1B_CN);
    unsigned short* wep_en = (unsigned short*)(ws + WEP_EN);
    unsigned short* wep_cn = (unsigned short*)(ws + WEP_CN);
    unsigned short* tep    = (unsigned short*)(ws + TEP);
    unsigned short* bt_en  = (unsigned short*)(ws + BT_EN);
    unsigned short* bt_cn  = (unsigned short*)(ws + BT_CN);
    unsigned short* thp_en = (unsigned short*)(ws + THP_EN);
    unsigned short* thp_cn = (unsigned short*)(ws + THP_CN);

    hipMemsetAsync(d_ws, 0, (size_t)ZERO_FLOATS * sizeof(float), stream);

    // ---- phase 1: encoder (XB alias of BIG region) ----
    cast_bf16_kernel<<<15000, 256, 0, stream>>>(x_en, xb_en, 3840000);
    cast_bf16_kernel<<<10000, 256, 0, stream>>>(x_cn, xb_cn, 2560000);
    transpose_cast_kernel<<<dim3(938, 16), 256, 0, stream>>>(W1_en, w1t_en, VEN, HID);
    transpose_cast_kernel<<<dim3(625, 16), 256, 0, stream>>>(W1_cn, w1t_cn, VCN, HID);
    transpose_cast_kernel<<<dim3(16, 16), 256, 0, stream>>>(W2_en, w2t_en, HID, HID);
    transpose_cast_kernel<<<dim3(16, 16), 256, 0, stream>>>(W2_cn, w2t_cn, HID, HID);

    mfma_gemm_nt<0><<<dim3(4, 4, 32), 256, 0, stream>>>(xb_en, w1t_en, ws + WS_H1_EN,
        BATCH, HID, VEN, VEN, VEN, 960, 0, nullptr, nullptr);
    mfma_gemm_nt<0><<<dim3(4, 4, 32), 256, 0, stream>>>(xb_cn, w1t_cn, ws + WS_H1_CN,
        BATCH, HID, VCN, VCN, VCN, 640, 0, nullptr, nullptr);

    bias_softplus_bf16_kernel<<<1024, 256, 0, stream>>>(ws + WS_H1_EN, b1_en, h1b_en, 262144);
    bias_softplus_bf16_kernel<<<1024, 256, 0, stream>>>(ws + WS_H1_CN, b1_cn, h1b_cn, 262144);

    mfma_gemm_nt<0><<<dim3(4, 4, 8), 256, 0, stream>>>(h1b_en, w2t_en, ws + WS_H2_EN,
        BATCH, HID, HID, HID, HID, 64, 0, nullptr, nullptr);
    mfma_gemm_nt<0><<<dim3(4, 4, 8), 256, 0, stream>>>(h1b_cn, w2t_cn, ws + WS_H2_CN,
        BATCH, HID, HID, HID, HID, 64, 0, nullptr, nullptr);

    bias_softplus_f32_kernel<<<1024, 256, 0, stream>>>(ws + WS_H2_EN, b2_en, 262144);
    bias_softplus_f32_kernel<<<1024, 256, 0, stream>>>(ws + WS_H2_CN, b2_cn, 262144);

    encoder_head_kernel<<<BATCH, 128, 0, stream>>>(ws + WS_H2_EN, Wmu_en, bmu_en, Wlv_en, blv_en,
                                                   eps_en, out + OUT_THETA_EN, ws + WS_SCAL + 0);
    encoder_head_kernel<<<BATCH, 128, 0, stream>>>(ws + WS_H2_CN, Wmu_cn, bmu_cn, Wlv_cn, blv_cn,
                                                   eps_cn, out + OUT_THETA_CN, ws + WS_SCAL + 1);

    // ---- phase 2: beta path (WEP/TEP overwrite XB region) ----
    padcast_kernel<<<VENP, KDP, 0, stream>>>(we_en, wep_en, VEN);
    padcast_kernel<<<VCNP, KDP, 0, stream>>>(we_cn, wep_cn, VCN);
    padcast_kernel<<<128, KDP, 0, stream>>>(te, tep, KT);
    sqnorm_rows_kernel<<<VEN, 64, 0, stream>>>(we_en, ws + WN2_EN, VEN, DIM);
    sqnorm_rows_kernel<<<VCN, 64, 0, stream>>>(we_cn, ws + WN2_CN, VCN, DIM);
    sqnorm_rows_kernel<<<KT, 64, 0, stream>>>(te, ws + TN2, KT, DIM);

    mfma_gemm_nt<2><<<dim3(235, 1, 1), 256, 0, stream>>>(wep_en, tep, out + OUT_BETA_EN,
        VENP, 128, KDP, KDP, KDP, KDP, VEN, ws + WN2_EN, ws + TN2);
    mfma_gemm_nt<2><<<dim3(157, 1, 1), 256, 0, stream>>>(wep_cn, tep, out + OUT_BETA_CN,
        VCNP, 128, KDP, KDP, KDP, KDP, VCN, ws + WN2_CN, ws + TN2);

    colsum_kernel<<<KT, 256, 0, stream>>>(out + OUT_BETA_EN, ws + WS_COLSUM_EN, VEN);
    colsum_kernel<<<KT, 256, 0, stream>>>(out + OUT_BETA_CN, ws + WS_COLSUM_CN, VCN);
    normbeta_kernel<<<dim3(118, KT), 256, 0, stream>>>(out + OUT_BETA_EN, ws + WS_COLSUM_EN, VEN);
    normbeta_kernel<<<dim3(79, KT), 256, 0, stream>>>(out + OUT_BETA_CN, ws + WS_COLSUM_CN, VCN);

    // ---- recon via MFMA ----
    beta_to_bt_kernel<<<VENP / 64, 256, 0, stream>>>(out + OUT_BETA_EN, bt_en, VEN);
    beta_to_bt_kernel<<<VCNP / 64, 256, 0, stream>>>(out + OUT_BETA_CN, bt_cn, VCN);
    theta_pad_kernel<<<256, 256, 0, stream>>>(out + OUT_THETA_EN, thp_en);
    theta_pad_kernel<<<256, 256, 0, stream>>>(out + OUT_THETA_CN, thp_cn);

    recon_mfma_kernel<<<dim3(VENP / 128, 4), 256, 0, stream>>>(bt_en, thp_en, x_en, VEN, ws + WS_ROWS_EN);
    recon_mfma_kernel<<<dim3(VCNP / 128, 4), 256, 0, stream>>>(bt_cn, thp_cn, x_cn, VCN, ws + WS_ROWS_CN);
    recon_finalize_kernel<<<2, 256, 0, stream>>>(ws + WS_ROWS_EN, ws + WS_ROWS_CN, ws + WS_SCAL);

    // ---- contrastive ----
    contrast_prep_kernel<<<BATCH, 128, 0, stream>>>(out + OUT_THETA_EN, out + OUT_THETA_CN, ws + WS_TNBUF);
    contrast_main_kernel<<<BATCH, 256, 0, stream>>>(ws + WS_TNBUF, cid, ws + WS_SCAL);

    // ---- alignment ----
    norm_rows_kernel<<<KT, 64, 0, stream>>>(te, ws + WS_TNT, DIM);
    ctopic_kernel<<<KT, 128, 0, stream>>>(ws + WS_TNT, ws + WS_CTOP);
    sinkhorn_kernel<<<1, 512, 0, stream>>>(ws + WS_CTOP, ws + WS_SCAL);

    final_combine_kernel<<<1, 64, 0, stream>>>(ws + WS_SCAL, out);
}

// Round 4
// 880.069 us; speedup vs baseline: 2.9282x; 1.0541x over previous
//
#include <hip/hip_runtime.h>
#include <math.h>

#define BATCH 512
#define VEN 30000
#define VCN 20000
#define KT 100
#define HID 512
#define DIM 300
#define VENP 30080   // padded to 128
#define VCNP 20096
#define KDP 320      // DIM padded to mult of 64

typedef float f32x4 __attribute__((ext_vector_type(4)));
typedef short bf16x8 __attribute__((ext_vector_type(8)));
typedef unsigned short u16x8 __attribute__((ext_vector_type(8)));
typedef unsigned short u16x4 __attribute__((ext_vector_type(4)));

// ---------------- workspace layout (float offsets) ----------------
#define WS_H1_EN   0
#define WS_H2_EN   (WS_H1_EN + 262144)
#define WS_H1_CN   (WS_H2_EN + 262144)
#define WS_H2_CN   (WS_H1_CN + 262144)
#define WS_ROWS_EN (WS_H2_CN + 262144)
#define WS_ROWS_CN (WS_ROWS_EN + 1536)
#define WS_SCAL    (WS_ROWS_CN + 1536)
#define ZERO_FLOATS (WS_SCAL + 64)
// BIG aliased region: phase 2 = WEP/TEP + BT/THP (phase 1 no longer uses it)
#define WS_BIG     ZERO_FLOATS
#define WEP_EN     WS_BIG                       // 4,812,800 f
#define WEP_CN     (WS_BIG + 4812800)           // 3,215,360 f
#define TEP        (WS_BIG + 4812800 + 3215360) // 20,480 f
#define BT_EN      (WS_BIG + 8048640)           // 30080*128 u16 = 1,925,120 f
#define BT_CN      (BT_EN + 1925120)            // 20096*128 u16 = 1,286,144 f
#define THP_EN     (BT_CN + 1286144)            // 512*128 u16 = 32,768 f
#define THP_CN     (THP_EN + 32768)
#define AFTER_BIG  (WS_BIG + 12800000)
#define W1T_EN     AFTER_BIG                    // 7,680,000 f
#define W1T_CN     (W1T_EN + 7680000)           // 5,120,000 f
#define W2T_EN     (W1T_CN + 5120000)           // 131072 f
#define W2T_CN     (W2T_EN + 131072)
#define H1B_EN     (W2T_CN + 131072)
#define H1B_CN     (H1B_EN + 131072)
#define WN2_EN     (H1B_CN + 131072)            // 30080
#define WN2_CN     (WN2_EN + 30080)             // 20096
#define TN2        (WN2_CN + 20096)             // 128
#define WS_TNBUF   (TN2 + 128)                  // 51200
#define WS_TNT     (WS_TNBUF + 51200)           // 30000
#define WS_CTOP    (WS_TNT + 30000)             // 10000
#define WS_COLSUM_EN (WS_CTOP + 10000)          // 128
#define WS_COLSUM_CN (WS_COLSUM_EN + 128)

// ---------------- output layout (float offsets) ----------------
#define OUT_THETA_EN 5
#define OUT_THETA_CN (OUT_THETA_EN + 51200)
#define OUT_BETA_EN  (OUT_THETA_CN + 51200)
#define OUT_BETA_CN  (OUT_BETA_EN + 3000000)

__device__ __forceinline__ float waveReduceSum(float v) {
    #pragma unroll
    for (int o = 32; o > 0; o >>= 1) v += __shfl_down(v, o);
    return v;
}

__device__ __forceinline__ unsigned short f2bf(float f) {
    unsigned int u = __float_as_uint(f);
    u = (u + 0x7FFFu + ((u >> 16) & 1u)) >> 16;   // RNE
    return (unsigned short)u;
}

// ================= bf16 MFMA GEMM (NT) =================
// A: AF32 ? fp32 (converted during staging) : bf16. B: bf16 [N][ldB] k-major.
// MODE 0: C[M][N] fp32 atomicAdd (split-K).
// MODE 2: beta epilogue.
template <int MODE, int AF32>
__global__ __launch_bounds__(256)
void mfma_gemm_nt(const void* __restrict__ Av, const unsigned short* __restrict__ B,
                  float* __restrict__ C, int M, int N, int K, int ldA, int ldB, int chunkK,
                  int Mreal, const float* __restrict__ an2, const float* __restrict__ bn2)
{
    __shared__ __align__(16) unsigned short As[128 * 40];
    __shared__ __align__(16) unsigned short Bs[128 * 40];
    const int tid = threadIdx.x;
    const int m0 = blockIdx.x * 128, n0 = blockIdx.y * 128;
    const int kStart = blockIdx.z * chunkK;
    const int kEnd = min(kStart + chunkK, K);

    const int wave = tid >> 6, lane = tid & 63;
    const int wm = (wave & 1) * 64, wn = (wave >> 1) * 64;
    const int l15 = lane & 15, quad = lane >> 4;

    const int srow = tid >> 1;
    const int scol = (tid & 1) * 16;

    f32x4 acc[4][4];
    #pragma unroll
    for (int i = 0; i < 4; ++i)
        #pragma unroll
        for (int j = 0; j < 4; ++j)
            acc[i][j] = (f32x4){0.f, 0.f, 0.f, 0.f};

    const u16x8 z8 = {0,0,0,0,0,0,0,0};

    for (int k0 = kStart; k0 < kEnd; k0 += 32) {
        int kA = k0 + scol;
        if (AF32) {
            const float* pa = (const float*)Av + (size_t)(m0 + srow) * ldA + kA;
            float4 f0 = {0,0,0,0}, f1 = {0,0,0,0}, f2 = {0,0,0,0}, f3 = {0,0,0,0};
            if (kA < kEnd) {   // K multiples of 16 -> whole 16-chunk valid
                f0 = *(const float4*)(pa);
                f1 = *(const float4*)(pa + 4);
                f2 = *(const float4*)(pa + 8);
                f3 = *(const float4*)(pa + 12);
            }
            u16x8 o0 = { f2bf(f0.x), f2bf(f0.y), f2bf(f0.z), f2bf(f0.w),
                         f2bf(f1.x), f2bf(f1.y), f2bf(f1.z), f2bf(f1.w) };
            u16x8 o1 = { f2bf(f2.x), f2bf(f2.y), f2bf(f2.z), f2bf(f2.w),
                         f2bf(f3.x), f2bf(f3.y), f2bf(f3.z), f2bf(f3.w) };
            *(u16x8*)&As[srow * 40 + scol]     = o0;
            *(u16x8*)&As[srow * 40 + scol + 8] = o1;
        } else {
            const unsigned short* pa = (const unsigned short*)Av + (size_t)(m0 + srow) * ldA + kA;
            u16x8 a0 = (kA     < kEnd) ? *(const u16x8*)(pa)     : z8;
            u16x8 a1 = (kA + 8 < kEnd) ? *(const u16x8*)(pa + 8) : z8;
            *(u16x8*)&As[srow * 40 + scol]     = a0;
            *(u16x8*)&As[srow * 40 + scol + 8] = a1;
        }
        {
            const unsigned short* pb = B + (size_t)(n0 + srow) * ldB + kA;
            u16x8 b0 = (kA     < kEnd) ? *(const u16x8*)(pb)     : z8;
            u16x8 b1 = (kA + 8 < kEnd) ? *(const u16x8*)(pb + 8) : z8;
            *(u16x8*)&Bs[srow * 40 + scol]     = b0;
            *(u16x8*)&Bs[srow * 40 + scol + 8] = b1;
        }
        __syncthreads();
        bf16x8 af[4], bfr[4];
        #pragma unroll
        for (int mi = 0; mi < 4; ++mi)
            af[mi] = *(const bf16x8*)&As[(wm + mi * 16 + l15) * 40 + quad * 8];
        #pragma unroll
        for (int ni = 0; ni < 4; ++ni)
            bfr[ni] = *(const bf16x8*)&Bs[(wn + ni * 16 + l15) * 40 + quad * 8];
        #pragma unroll
        for (int mi = 0; mi < 4; ++mi)
            #pragma unroll
            for (int ni = 0; ni < 4; ++ni)
                acc[mi][ni] = __builtin_amdgcn_mfma_f32_16x16x32_bf16(af[mi], bfr[ni], acc[mi][ni], 0, 0, 0);
        __syncthreads();
    }

    if (MODE == 0) {
        #pragma unroll
        for (int mi = 0; mi < 4; ++mi)
            #pragma unroll
            for (int ni = 0; ni < 4; ++ni)
                #pragma unroll
                for (int i = 0; i < 4; ++i) {
                    int m = m0 + wm + mi * 16 + quad * 4 + i;
                    int n = n0 + wn + ni * 16 + l15;
                    atomicAdd(&C[(size_t)m * N + n], acc[mi][ni][i]);
                }
    } else {
        #pragma unroll
        for (int mi = 0; mi < 4; ++mi)
            #pragma unroll
            for (int ni = 0; ni < 4; ++ni)
                #pragma unroll
                for (int i = 0; i < 4; ++i) {
                    int m = m0 + wm + mi * 16 + quad * 4 + i;
                    int n = n0 + wn + ni * 16 + l15;
                    if (m < Mreal && n < KT) {
                        float sq = an2[m] + bn2[n] - 2.f * acc[mi][ni][i];
                        C[(size_t)n * Mreal + m] = __expf(-sqrtf(fmaxf(sq, 0.f)));
                    }
                }
    }
}

// ============ recon MFMA: r = betaT[V][K] x thetaPad[B][K]; fused loss sums ============
__global__ __launch_bounds__(256)
void recon_mfma_kernel(const unsigned short* __restrict__ A, const unsigned short* __restrict__ B,
                       const float* __restrict__ x, int V, float* __restrict__ rows)
{
    __shared__ __align__(16) unsigned short As[128 * 40];
    __shared__ __align__(16) unsigned short Bs[128 * 40];
    const int tid = threadIdx.x;
    const int m0 = blockIdx.x * 128, n0 = blockIdx.y * 128;
    const int wave = tid >> 6, lane = tid & 63;
    const int wm = (wave & 1) * 64, wn = (wave >> 1) * 64;
    const int l15 = lane & 15, quad = lane >> 4;
    const int srow = tid >> 1, scol = (tid & 1) * 16;

    f32x4 acc[4][4];
    #pragma unroll
    for (int i = 0; i < 4; ++i)
        #pragma unroll
        for (int j = 0; j < 4; ++j)
            acc[i][j] = (f32x4){0.f, 0.f, 0.f, 0.f};

    for (int k0 = 0; k0 < 128; k0 += 32) {
        int kA = k0 + scol;
        *(u16x8*)&As[srow * 40 + scol]     = *(const u16x8*)(A + (size_t)(m0 + srow) * 128 + kA);
        *(u16x8*)&As[srow * 40 + scol + 8] = *(const u16x8*)(A + (size_t)(m0 + srow) * 128 + kA + 8);
        *(u16x8*)&Bs[srow * 40 + scol]     = *(const u16x8*)(B + (size_t)(n0 + srow) * 128 + kA);
        *(u16x8*)&Bs[srow * 40 + scol + 8] = *(const u16x8*)(B + (size_t)(n0 + srow) * 128 + kA + 8);
        __syncthreads();
        bf16x8 af[4], bfr[4];
        #pragma unroll
        for (int mi = 0; mi < 4; ++mi)
            af[mi] = *(const bf16x8*)&As[(wm + mi * 16 + l15) * 40 + quad * 8];
        #pragma unroll
        for (int ni = 0; ni < 4; ++ni)
            bfr[ni] = *(const bf16x8*)&Bs[(wn + ni * 16 + l15) * 40 + quad * 8];
        #pragma unroll
        for (int mi = 0; mi < 4; ++mi)
            #pragma unroll
            for (int ni = 0; ni < 4; ++ni)
                acc[mi][ni] = __builtin_amdgcn_mfma_f32_16x16x32_bf16(af[mi], bfr[ni], acc[mi][ni], 0, 0, 0);
        __syncthreads();
    }

    #pragma unroll
    for (int ni = 0; ni < 4; ++ni) {
        int b = n0 + wn + ni * 16 + l15;
        float tse = 0.f, tsxr = 0.f, tsx = 0.f;
        #pragma unroll
        for (int mi = 0; mi < 4; ++mi) {
            int v0 = m0 + wm + mi * 16 + quad * 4;
            if (v0 + 3 < V) {
                float4 xv = *(const float4*)&x[(size_t)b * V + v0];
                float xa[4] = {xv.x, xv.y, xv.z, xv.w};
                #pragma unroll
                for (int i = 0; i < 4; ++i) {
                    float r = acc[mi][ni][i];
                    tse += __expf(r);
                    tsxr += xa[i] * r;
                    tsx  += xa[i];
                }
            } else {
                #pragma unroll
                for (int i = 0; i < 4; ++i) {
                    int v = v0 + i;
                    if (v < V) {
                        float xv1 = x[(size_t)b * V + v];
                        float r = acc[mi][ni][i];
                        tse += __expf(r); tsxr += xv1 * r; tsx += xv1;
                    }
                }
            }
        }
        tse  += __shfl_xor(tse, 16);  tse  += __shfl_xor(tse, 32);
        tsxr += __shfl_xor(tsxr, 16); tsxr += __shfl_xor(tsxr, 32);
        tsx  += __shfl_xor(tsx, 16);  tsx  += __shfl_xor(tsx, 32);
        if (quad == 0) {
            atomicAdd(&rows[b], tse);
            atomicAdd(&rows[512 + b], tsxr);
            atomicAdd(&rows[1024 + b], tsx);
        }
    }
}

// ================= cast / transpose kernels =================
__global__ __launch_bounds__(256)
void transpose_cast_kernel(const float* __restrict__ src, unsigned short* __restrict__ dst,
                           int K, int N)
{
    __shared__ float tile[32][33];
    int kb = blockIdx.x * 32, nb = blockIdx.y * 32;
    int tx = threadIdx.x & 31, ty4 = threadIdx.x >> 5;
    #pragma unroll
    for (int j = 0; j < 4; ++j) {
        int k = kb + ty4 * 4 + j;
        tile[ty4 * 4 + j][tx] = (k < K) ? src[(size_t)k * N + nb + tx] : 0.f;
    }
    __syncthreads();
    #pragma unroll
    for (int j = 0; j < 4; ++j) {
        int n = nb + ty4 * 4 + j;
        int k = kb + tx;
        if (k < K) dst[(size_t)n * K + k] = f2bf(tile[tx][ty4 * 4 + j]);
    }
}

// fused: word_emb [V][300] f32 -> [Vp][320] bf16 zero-padded + row sqnorm
__global__ void padcast_sqnorm_kernel(const float* __restrict__ src, unsigned short* __restrict__ dst,
                                      float* __restrict__ n2, int V)
{
    int m = blockIdx.x, tid = threadIdx.x;   // 64 threads
    float sq = 0.f;
    #pragma unroll
    for (int j = 0; j < 5; ++j) {
        int k = tid + j * 64;
        float v = (m < V && k < DIM) ? src[(size_t)m * DIM + k] : 0.f;
        dst[(size_t)m * KDP + k] = f2bf(v);
        sq += v * v;
    }
    sq = waveReduceSum(sq);
    if (tid == 0) n2[m] = sq;
}

// fused: normalize beta in place (f32, out buffer) + build bt [Vp][128] bf16
__global__ __launch_bounds__(256)
void normbeta_bt_kernel(float* __restrict__ beta, const float* __restrict__ cs,
                        unsigned short* __restrict__ bt, int V)
{
    int v = blockIdx.x * 64 + (threadIdx.x & 63);
    int kq = threadIdx.x >> 6;   // 0..3
    unsigned short tmp[32];
    #pragma unroll
    for (int j = 0; j < 32; ++j) {
        int k = kq * 32 + j;
        float val = 0.f;
        if (k < KT && v < V) {
            val = beta[(size_t)k * V + v] * (1.0f / cs[k]);
            beta[(size_t)k * V + v] = val;
        }
        tmp[j] = f2bf(val);
    }
    #pragma unroll
    for (int q = 0; q < 4; ++q)
        *(u16x8*)&bt[(size_t)v * 128 + kq * 32 + q * 8] = *(u16x8*)&tmp[q * 8];
}

__global__ void theta_pad_kernel(const float* __restrict__ theta, unsigned short* __restrict__ thp)
{
    int idx = blockIdx.x * 256 + threadIdx.x;  // 65536 total
    int b = idx >> 7, k = idx & 127;
    thp[idx] = f2bf(k < KT ? theta[b * KT + k] : 0.f);
}

__global__ __launch_bounds__(256)
void colsum_kernel(const float* __restrict__ bta, float* __restrict__ cs, int V)
{
    int k = blockIdx.x, tid = threadIdx.x;
    float s = 0.f;
    for (int v = tid; v < V; v += 256) s += bta[(size_t)k * V + v];
    s = waveReduceSum(s);
    __shared__ float cw[4];
    if ((tid & 63) == 0) cw[tid >> 6] = s;
    __syncthreads();
    if (tid == 0) cs[k] = cw[0] + cw[1] + cw[2] + cw[3];
}

__global__ void bias_softplus_bf16_kernel(const float* __restrict__ src, const float* __restrict__ b,
                                          unsigned short* __restrict__ dst, int n)
{
    int i = blockIdx.x * 256 + threadIdx.x;
    if (i < n) {
        float x = src[i] + b[i & (HID - 1)];
        float sp = fmaxf(x, 0.f) + log1pf(__expf(-fabsf(x)));
        dst[i] = f2bf(sp);
    }
}

__global__ void bias_softplus_f32_kernel(float* __restrict__ y, const float* __restrict__ b, int n)
{
    int i = blockIdx.x * 256 + threadIdx.x;
    if (i < n) {
        float x = y[i] + b[i & (HID - 1)];
        y[i] = fmaxf(x, 0.f) + log1pf(__expf(-fabsf(x)));
    }
}

// ================= encoder head =================
__global__ __launch_bounds__(128)
void encoder_head_kernel(const float* __restrict__ h2, const float* __restrict__ Wmu,
                         const float* __restrict__ bmu, const float* __restrict__ Wlv,
                         const float* __restrict__ blv, const float* __restrict__ eps,
                         float* __restrict__ theta_out, float* __restrict__ kl_accum)
{
    int i = blockIdx.x, tid = threadIdx.x;
    __shared__ float hrow[HID];
    __shared__ float sred[128];
    #pragma unroll
    for (int j = 0; j < 4; ++j) hrow[tid + 128 * j] = h2[i * HID + tid + 128 * j];
    __syncthreads();
    float mu = 0.f, lv = 0.f;
    if (tid < KT) {
        #pragma unroll 8
        for (int h = 0; h < HID; ++h) {
            float hv = hrow[h];
            mu += hv * Wmu[h * KT + tid];
            lv += hv * Wlv[h * KT + tid];
        }
        mu += bmu[tid]; lv += blv[tid];
    }
    float z = (tid < KT) ? (mu + eps[i * KT + tid] * __expf(0.5f * lv)) : -3.0e38f;
    sred[tid] = z; __syncthreads();
    for (int s = 64; s > 0; s >>= 1) { if (tid < s) sred[tid] = fmaxf(sred[tid], sred[tid + s]); __syncthreads(); }
    float zmax = sred[0]; __syncthreads();
    float e = (tid < KT) ? __expf(z - zmax) : 0.f;
    sred[tid] = e; __syncthreads();
    for (int s = 64; s > 0; s >>= 1) { if (tid < s) sred[tid] += sred[tid + s]; __syncthreads(); }
    float esum = sred[0]; __syncthreads();
    if (tid < KT) theta_out[i * KT + tid] = e / esum;
    float kterm = (tid < KT) ? 0.5f * (__expf(lv) + mu * mu - 1.f - lv) : 0.f;
    sred[tid] = kterm; __syncthreads();
    for (int s = 64; s > 0; s >>= 1) { if (tid < s) sred[tid] += sred[tid + s]; __syncthreads(); }
    if (tid == 0) atomicAdd(kl_accum, sred[0]);
}

__global__ __launch_bounds__(256)
void recon_finalize_kernel(const float* __restrict__ rows_en, const float* __restrict__ rows_cn,
                           float* __restrict__ scal)
{
    const float* rows = (blockIdx.x == 0) ? rows_en : rows_cn;
    int tid = threadIdx.x;
    float s = 0.f;
    for (int r = tid; r < 512; r += 256) {
        float se = rows[r], sxr = rows[512 + r], sx = rows[1024 + r];
        s += __logf(se) * sx - sxr;
    }
    s = waveReduceSum(s);
    __shared__ float cw[4];
    if ((tid & 63) == 0) cw[tid >> 6] = s;
    __syncthreads();
    if (tid == 0) scal[5 + blockIdx.x] = cw[0] + cw[1] + cw[2] + cw[3];
}

// ================= contrastive =================
__global__ __launch_bounds__(128)
void contrast_prep_kernel(const float* __restrict__ theta_en, const float* __restrict__ theta_cn,
                          float* __restrict__ tn)
{
    int i = blockIdx.x, tid = threadIdx.x;
    const float* src = ((i & 1) == 0) ? theta_en : theta_cn;
    float val = (tid < KT) ? src[i * KT + tid] : 0.f;
    __shared__ float sred[128];
    sred[tid] = val * val; __syncthreads();
    for (int s = 64; s > 0; s >>= 1) { if (tid < s) sred[tid] += sred[tid + s]; __syncthreads(); }
    float inv = 1.0f / fmaxf(sqrtf(sred[0]), 1e-8f);
    if (tid < KT) tn[i * KT + tid] = val * inv;
}

__global__ __launch_bounds__(256)
void contrast_main_kernel(const float* __restrict__ tn, const int* __restrict__ cid,
                          float* __restrict__ scal)
{
    int i = blockIdx.x, tid = threadIdx.x;
    __shared__ __align__(16) float ti[KT];
    if (tid < KT) ti[tid] = tn[i * KT + tid];
    __syncthreads();
    int ci = cid[i];
    bool vi = ci > 0;
    float pos = 0.f, neg = 0.f, pcnt = 0.f;
    for (int j = tid; j < 512; j += 256) {
        if (j == i) continue;
        float s = 0.f;
        const float4* tj = reinterpret_cast<const float4*>(&tn[j * KT]);
        #pragma unroll
        for (int q = 0; q < 25; ++q) {
            float4 t4 = tj[q];
            s += ti[4 * q] * t4.x + ti[4 * q + 1] * t4.y + ti[4 * q + 2] * t4.z + ti[4 * q + 3] * t4.w;
        }
        float E = __expf(s);
        neg += E;
        if (vi && cid[j] == ci) { pos += E; pcnt += 1.f; }
    }
    pos = waveReduceSum(pos); neg = waveReduceSum(neg); pcnt = waveReduceSum(pcnt);
    __shared__ float cw[3][4];
    int w = tid >> 6;
    if ((tid & 63) == 0) { cw[0][w] = pos; cw[1][w] = neg; cw[2][w] = pcnt; }
    __syncthreads();
    if (tid == 0) {
        float P = 0.f, N = 0.f, PC = 0.f;
        for (int q = 0; q < 4; ++q) { P += cw[0][q]; N += cw[1][q]; PC += cw[2][q]; }
        if (vi && PC > 0.f) {
            atomicAdd(&scal[2], -__logf(P / (P + N + 1e-8f)));
            atomicAdd(&scal[3], 1.0f);
        }
    }
}

// ================= alignment / sinkhorn =================
__global__ void norm_rows_kernel(const float* __restrict__ A, float* __restrict__ out, int cols)
{
    int r = blockIdx.x, tid = threadIdx.x;
    float s = 0.f;
    for (int d = tid; d < cols; d += 64) { float a = A[r * cols + d]; s += a * a; }
    s = waveReduceSum(s);
    s = __shfl(s, 0);
    float inv = 1.0f / fmaxf(sqrtf(s), 1e-8f);
    for (int d = tid; d < cols; d += 64) out[r * cols + d] = A[r * cols + d] * inv;
}

__global__ __launch_bounds__(128)
void ctopic_kernel(const float* __restrict__ tnt, float* __restrict__ C)
{
    int i = blockIdx.x, tid = threadIdx.x;
    __shared__ float ti[DIM];
    for (int d = tid; d < DIM; d += 128) ti[d] = tnt[i * DIM + d];
    __syncthreads();
    for (int j = tid; j < KT; j += 128) {
        float s = 0.f;
        for (int d = 0; d < DIM; ++d) s += ti[d] * tnt[j * DIM + d];
        C[i * KT + j] = 1.0f - s;
    }
}

// register-resident sinkhorn: 2 waves, thread t owns row t (K) and col t (K^T)
__global__ __launch_bounds__(128, 1)
void sinkhorn_kernel(const float* __restrict__ C, float* __restrict__ scal)
{
    __shared__ __align__(16) float ld[100 * 101];
    __shared__ __align__(16) float ub[128], vb[128];
    __shared__ float cw[2];
    const int tid = threadIdx.x;

    for (int i = tid; i < 10000; i += 128) {
        int r = i / 100, c = i - r * 100;
        ld[r * 101 + c] = C[i];
    }
    ub[tid] = 1.f; vb[tid] = 1.f;
    __syncthreads();

    float kr[100], kc[100];
    if (tid < 100) {
        #pragma unroll
        for (int j = 0; j < 100; ++j) kr[j] = __expf(-10.f * ld[tid * 101 + j]);
        #pragma unroll
        for (int j = 0; j < 100; ++j) kc[j] = __expf(-10.f * ld[j * 101 + tid]);
    }

    for (int it = 0; it < 50; ++it) {
        if (tid < 100) {
            float s = 0.f;
            #pragma unroll
            for (int q = 0; q < 25; ++q) {
                float4 v4 = *(const float4*)&vb[q * 4];
                s += kr[q*4]*v4.x + kr[q*4+1]*v4.y + kr[q*4+2]*v4.z + kr[q*4+3]*v4.w;
            }
            ub[tid] = 0.01f / (s + 1e-8f);
        }
        __syncthreads();
        if (tid < 100) {
            float s = 0.f;
            #pragma unroll
            for (int q = 0; q < 25; ++q) {
                float4 u4 = *(const float4*)&ub[q * 4];
                s += kc[q*4]*u4.x + kc[q*4+1]*u4.y + kc[q*4+2]*u4.z + kc[q*4+3]*u4.w;
            }
            vb[tid] = 0.01f / (s + 1e-8f);
        }
        __syncthreads();
    }

    // loss = sum_ij u_i K_ij v_j C_ij
    float part = 0.f;
    if (tid < 100) {
        float u = ub[tid];
        #pragma unroll
        for (int q = 0; q < 25; ++q) {
            float4 v4 = *(const float4*)&vb[q * 4];
            float va[4] = {v4.x, v4.y, v4.z, v4.w};
            #pragma unroll
            for (int e = 0; e < 4; ++e) {
                int j = q * 4 + e;
                part += u * kr[j] * va[e] * ld[tid * 101 + j];
            }
        }
    }
    part = waveReduceSum(part);
    if ((tid & 63) == 0) cw[tid >> 6] = part;
    __syncthreads();
    if (tid == 0) scal[4] = cw[0] + cw[1];
}

__global__ void final_combine_kernel(const float* __restrict__ scal, float* __restrict__ out)
{
    if (threadIdx.x == 0 && blockIdx.x == 0) {
        const float invB = 1.0f / 512.0f;
        float tm_en = scal[5] * invB + scal[0] * invB;
        float tm_cn = scal[6] * invB + scal[1] * invB;
        float contrast = scal[2] / (scal[3] + 1e-8f);
        float align = scal[4];
        out[0] = tm_en + tm_cn + contrast + align;
        out[1] = tm_en;
        out[2] = tm_cn;
        out[3] = contrast;
        out[4] = align;
    }
}

// ================= launch =================
extern "C" void kernel_launch(void* const* d_in, const int* in_sizes, int n_in,
                              void* d_out_v, int out_size, void* d_ws, size_t ws_size,
                              hipStream_t stream)
{
    const float* x_en   = (const float*)d_in[0];
    const float* x_cn   = (const float*)d_in[1];
    const int*   cid    = (const int*)  d_in[2];
    const float* eps_en = (const float*)d_in[3];
    const float* eps_cn = (const float*)d_in[4];
    const float* W1_en  = (const float*)d_in[5];
    const float* b1_en  = (const float*)d_in[6];
    const float* W2_en  = (const float*)d_in[7];
    const float* b2_en  = (const float*)d_in[8];
    const float* Wmu_en = (const float*)d_in[9];
    const float* bmu_en = (const float*)d_in[10];
    const float* Wlv_en = (const float*)d_in[11];
    const float* blv_en = (const float*)d_in[12];
    const float* W1_cn  = (const float*)d_in[13];
    const float* b1_cn  = (const float*)d_in[14];
    const float* W2_cn  = (const float*)d_in[15];
    const float* b2_cn  = (const float*)d_in[16];
    const float* Wmu_cn = (const float*)d_in[17];
    const float* bmu_cn = (const float*)d_in[18];
    const float* Wlv_cn = (const float*)d_in[19];
    const float* blv_cn = (const float*)d_in[20];
    const float* we_en  = (const float*)d_in[21];
    const float* we_cn  = (const float*)d_in[22];
    const float* te     = (const float*)d_in[23];
    float* out = (float*)d_out_v;
    float* ws  = (float*)d_ws;

    unsigned short* w1t_en = (unsigned short*)(ws + W1T_EN);
    unsigned short* w1t_cn = (unsigned short*)(ws + W1T_CN);
    unsigned short* w2t_en = (unsigned short*)(ws + W2T_EN);
    unsigned short* w2t_cn = (unsigned short*)(ws + W2T_CN);
    unsigned short* h1b_en = (unsigned short*)(ws + H1B_EN);
    unsigned short* h1b_cn = (unsigned short*)(ws + H1B_CN);
    unsigned short* wep_en = (unsigned short*)(ws + WEP_EN);
    unsigned short* wep_cn = (unsigned short*)(ws + WEP_CN);
    unsigned short* tep    = (unsigned short*)(ws + TEP);
    unsigned short* bt_en  = (unsigned short*)(ws + BT_EN);
    unsigned short* bt_cn  = (unsigned short*)(ws + BT_CN);
    unsigned short* thp_en = (unsigned short*)(ws + THP_EN);
    unsigned short* thp_cn = (unsigned short*)(ws + THP_CN);

    hipMemsetAsync(d_ws, 0, (size_t)ZERO_FLOATS * sizeof(float), stream);

    // ---- phase 1: encoders (x cast fused into gemm1 staging) ----
    transpose_cast_kernel<<<dim3(938, 16), 256, 0, stream>>>(W1_en, w1t_en, VEN, HID);
    transpose_cast_kernel<<<dim3(625, 16), 256, 0, stream>>>(W1_cn, w1t_cn, VCN, HID);
    transpose_cast_kernel<<<dim3(16, 16), 256, 0, stream>>>(W2_en, w2t_en, HID, HID);
    transpose_cast_kernel<<<dim3(16, 16), 256, 0, stream>>>(W2_cn, w2t_cn, HID, HID);

    mfma_gemm_nt<0, 1><<<dim3(4, 4, 32), 256, 0, stream>>>(x_en, w1t_en, ws + WS_H1_EN,
        BATCH, HID, VEN, VEN, VEN, 960, 0, nullptr, nullptr);
    mfma_gemm_nt<0, 1><<<dim3(4, 4, 32), 256, 0, stream>>>(x_cn, w1t_cn, ws + WS_H1_CN,
        BATCH, HID, VCN, VCN, VCN, 640, 0, nullptr, nullptr);

    bias_softplus_bf16_kernel<<<1024, 256, 0, stream>>>(ws + WS_H1_EN, b1_en, h1b_en, 262144);
    bias_softplus_bf16_kernel<<<1024, 256, 0, stream>>>(ws + WS_H1_CN, b1_cn, h1b_cn, 262144);

    mfma_gemm_nt<0, 0><<<dim3(4, 4, 8), 256, 0, stream>>>(h1b_en, w2t_en, ws + WS_H2_EN,
        BATCH, HID, HID, HID, HID, 64, 0, nullptr, nullptr);
    mfma_gemm_nt<0, 0><<<dim3(4, 4, 8), 256, 0, stream>>>(h1b_cn, w2t_cn, ws + WS_H2_CN,
        BATCH, HID, HID, HID, HID, 64, 0, nullptr, nullptr);

    bias_softplus_f32_kernel<<<1024, 256, 0, stream>>>(ws + WS_H2_EN, b2_en, 262144);
    bias_softplus_f32_kernel<<<1024, 256, 0, stream>>>(ws + WS_H2_CN, b2_cn, 262144);

    encoder_head_kernel<<<BATCH, 128, 0, stream>>>(ws + WS_H2_EN, Wmu_en, bmu_en, Wlv_en, blv_en,
                                                   eps_en, out + OUT_THETA_EN, ws + WS_SCAL + 0);
    encoder_head_kernel<<<BATCH, 128, 0, stream>>>(ws + WS_H2_CN, Wmu_cn, bmu_cn, Wlv_cn, blv_cn,
                                                   eps_cn, out + OUT_THETA_CN, ws + WS_SCAL + 1);

    // ---- phase 2: beta path ----
    padcast_sqnorm_kernel<<<VENP, 64, 0, stream>>>(we_en, wep_en, ws + WN2_EN, VEN);
    padcast_sqnorm_kernel<<<VCNP, 64, 0, stream>>>(we_cn, wep_cn, ws + WN2_CN, VCN);
    padcast_sqnorm_kernel<<<128, 64, 0, stream>>>(te, tep, ws + TN2, KT);

    mfma_gemm_nt<2, 0><<<dim3(235, 1, 1), 256, 0, stream>>>(wep_en, tep, out + OUT_BETA_EN,
        VENP, 128, KDP, KDP, KDP, KDP, VEN, ws + WN2_EN, ws + TN2);
    mfma_gemm_nt<2, 0><<<dim3(157, 1, 1), 256, 0, stream>>>(wep_cn, tep, out + OUT_BETA_CN,
        VCNP, 128, KDP, KDP, KDP, KDP, VCN, ws + WN2_CN, ws + TN2);

    colsum_kernel<<<KT, 256, 0, stream>>>(out + OUT_BETA_EN, ws + WS_COLSUM_EN, VEN);
    colsum_kernel<<<KT, 256, 0, stream>>>(out + OUT_BETA_CN, ws + WS_COLSUM_CN, VCN);

    normbeta_bt_kernel<<<VENP / 64, 256, 0, stream>>>(out + OUT_BETA_EN, ws + WS_COLSUM_EN, bt_en, VEN);
    normbeta_bt_kernel<<<VCNP / 64, 256, 0, stream>>>(out + OUT_BETA_CN, ws + WS_COLSUM_CN, bt_cn, VCN);

    // ---- recon via MFMA ----
    theta_pad_kernel<<<256, 256, 0, stream>>>(out + OUT_THETA_EN, thp_en);
    theta_pad_kernel<<<256, 256, 0, stream>>>(out + OUT_THETA_CN, thp_cn);

    recon_mfma_kernel<<<dim3(VENP / 128, 4), 256, 0, stream>>>(bt_en, thp_en, x_en, VEN, ws + WS_ROWS_EN);
    recon_mfma_kernel<<<dim3(VCNP / 128, 4), 256, 0, stream>>>(bt_cn, thp_cn, x_cn, VCN, ws + WS_ROWS_CN);
    recon_finalize_kernel<<<2, 256, 0, stream>>>(ws + WS_ROWS_EN, ws + WS_ROWS_CN, ws + WS_SCAL);

    // ---- contrastive ----
    contrast_prep_kernel<<<BATCH, 128, 0, stream>>>(out + OUT_THETA_EN, out + OUT_THETA_CN, ws + WS_TNBUF);
    contrast_main_kernel<<<BATCH, 256, 0, stream>>>(ws + WS_TNBUF, cid, ws + WS_SCAL);

    // ---- alignment ----
    norm_rows_kernel<<<KT, 64, 0, stream>>>(te, ws + WS_TNT, DIM);
    ctopic_kernel<<<KT, 128, 0, stream>>>(ws + WS_TNT, ws + WS_CTOP);
    sinkhorn_kernel<<<1, 128, 0, stream>>>(ws + WS_CTOP, ws + WS_SCAL);

    final_combine_kernel<<<1, 64, 0, stream>>>(ws + WS_SCAL, out);
}